// Round 6
// baseline (1151.255 us; speedup 1.0000x reference)
//
#include <hip/hip_runtime.h>
#include <math.h>
#include <stdint.h>

// GPT fwd, L=4 D=1024 H=16 HS=64 F=4096 V=50257 S=2048.
// Round 6: unified gemm4 = 128x128 tile, BK=32, 4 waves, 3x16KB LDS buffers
// (3 blocks/CU co-residency), prefetch distance 2, counted vmcnt(4),
// 2-row-granular chunk-XOR swizzle, setprio, XCD-bijective block swizzle.

#define SEQ 2048
#define DIM 1024
#define NHEAD 16
#define FFN 4096
#define VOCAB 50257
#define NLAYER 4
#define LNEPS 1e-5f
#define QKVD 3072
#define KVB 128

using bf16x8 = __attribute__((ext_vector_type(8))) short;
using s16x4  = __attribute__((ext_vector_type(4))) short;
using f32x4  = __attribute__((ext_vector_type(4))) float;
using fl4    = __attribute__((ext_vector_type(4))) float;

static __device__ __forceinline__ short f2bf(float f) {
  uint32_t u = __float_as_uint(f);
  u = (u + 0x7fffu + ((u >> 16) & 1u)) >> 16;
  return (short)u;
}
static __device__ __forceinline__ float bf2f(short s) {
  return __uint_as_float(((uint32_t)(uint16_t)s) << 16);
}
static __device__ __forceinline__ void gload_lds16(const void* g, void* l) {
  __builtin_amdgcn_global_load_lds((const __attribute__((address_space(1))) void*)g,
                                   (__attribute__((address_space(3))) void*)l, 16, 0, 0);
}

// ---------------- embedding (fp32 h) ----------------
__global__ void embed_kernel(const int* __restrict__ ids,
                             const float* __restrict__ tok,
                             const float* __restrict__ pos,
                             float* __restrict__ h) {
  int i = blockIdx.x * blockDim.x + threadIdx.x;
  if (i < SEQ * DIM) {
    int s = i / DIM, d = i % DIM;
    h[i] = tok[(long)ids[s] * DIM + d] + pos[i];
  }
}

// ---------------- layernorm: fp32 in -> bf16 out ----------------
__global__ void ln_kernel(const float* __restrict__ x, const float* __restrict__ w,
                          const float* __restrict__ b, short* __restrict__ y) {
  int row = blockIdx.x;
  const float* xr = x + (long)row * DIM;
  short* yr = y + (long)row * DIM;
  int tid = threadIdx.x;
  float v0 = xr[tid], v1 = xr[tid + 256], v2 = xr[tid + 512], v3 = xr[tid + 768];
  __shared__ float red[8];
  float s = v0 + v1 + v2 + v3;
#pragma unroll
  for (int o = 32; o >= 1; o >>= 1) s += __shfl_xor(s, o);
  if ((tid & 63) == 0) red[tid >> 6] = s;
  __syncthreads();
  float mean = (red[0] + red[1] + red[2] + red[3]) * (1.f / DIM);
  float d0 = v0 - mean, d1 = v1 - mean, d2 = v2 - mean, d3 = v3 - mean;
  float q = d0 * d0 + d1 * d1 + d2 * d2 + d3 * d3;
#pragma unroll
  for (int o = 32; o >= 1; o >>= 1) q += __shfl_xor(q, o);
  if ((tid & 63) == 0) red[4 + (tid >> 6)] = q;
  __syncthreads();
  float var = (red[4] + red[5] + red[6] + red[7]) * (1.f / DIM);
  float rstd = rsqrtf(var + LNEPS);
  yr[tid]       = f2bf(d0 * rstd * w[tid] + b[tid]);
  yr[tid + 256] = f2bf(d1 * rstd * w[tid + 256] + b[tid + 256]);
  yr[tid + 512] = f2bf(d2 * rstd * w[tid + 512] + b[tid + 512]);
  yr[tid + 768] = f2bf(d3 * rstd * w[tid + 768] + b[tid + 768]);
}

// ---------------- weight transpose+convert: [K][N] fp32 -> [N][K] bf16 ----------------
__global__ void transpose_w(const float* __restrict__ in, short* __restrict__ out,
                            int K, int N) {
  __shared__ float t[32][33];
  int c0 = blockIdx.x * 32, r0 = blockIdx.y * 32;
  int tx = threadIdx.x & 31, ty = threadIdx.x >> 5;
#pragma unroll
  for (int i = 0; i < 4; i++)
    t[ty + i * 8][tx] = in[(long)(r0 + ty + i * 8) * N + c0 + tx];
  __syncthreads();
#pragma unroll
  for (int i = 0; i < 4; i++)
    out[(long)(c0 + ty + i * 8) * K + r0 + tx] = f2bf(t[tx][ty + i * 8]);
}

// batched 1024x1024 transposes (Wq,Wk,Wv,Wo) in one launch, z picks matrix
struct TW4 { const float* src[4]; short* dst[4]; };
__global__ void transpose_w4(TW4 p) {
  const float* in = p.src[blockIdx.z];
  short* out = p.dst[blockIdx.z];
  __shared__ float t[32][33];
  int c0 = blockIdx.x * 32, r0 = blockIdx.y * 32;
  int tx = threadIdx.x & 31, ty = threadIdx.x >> 5;
#pragma unroll
  for (int i = 0; i < 4; i++)
    t[ty + i * 8][tx] = in[(long)(r0 + ty + i * 8) * DIM + c0 + tx];
  __syncthreads();
#pragma unroll
  for (int i = 0; i < 4; i++)
    out[(long)(c0 + ty + i * 8) * DIM + r0 + tx] = f2bf(t[tx][ty + i * 8]);
}

// ---------------- V transpose: qkv[s][2D+c] -> vt[c][s], b128 both sides ----------------
__global__ void transpose_v(const short* __restrict__ qkv, short* __restrict__ vt) {
  __shared__ short t[64][72];
  int s0 = blockIdx.x * 64, c0 = blockIdx.y * 64;
  int tid = threadIdx.x;
#pragma unroll
  for (int i = 0; i < 2; i++) {
    int ca = i * 256 + tid;
    int row = ca >> 3, cp = ca & 7;
    bf16x8 v = *(const bf16x8*)(qkv + (long)(s0 + row) * QKVD + 2 * DIM + c0 + cp * 8);
    *(bf16x8*)&t[row][cp * 8] = v;
  }
  __syncthreads();
#pragma unroll
  for (int i = 0; i < 2; i++) {
    int ca = i * 256 + tid;
    int crow = ca >> 3, sp = ca & 7;
    s16x4 a, b;
#pragma unroll
    for (int u = 0; u < 4; u++) a[u] = t[sp * 8 + u][crow];
#pragma unroll
    for (int u = 0; u < 4; u++) b[u] = t[sp * 8 + 4 + u][crow];
    bf16x8 o;
#pragma unroll
    for (int u = 0; u < 4; u++) { o[u] = a[u]; o[4 + u] = b[u]; }
    *(bf16x8*)(vt + (long)(c0 + crow) * SEQ + s0 + sp * 8) = o;
  }
}

// ---------------- fp32 -> bf16 convert (lm_head) ----------------
__global__ void conv_bf16(const float* __restrict__ in, short* __restrict__ out, long n4) {
  long i = (long)blockIdx.x * blockDim.x + threadIdx.x;
  long stride = (long)gridDim.x * blockDim.x;
  for (; i < n4; i += stride) {
    fl4 v = *(const fl4*)(in + i * 4);
    s16x4 o;
    o[0] = f2bf(v[0]); o[1] = f2bf(v[1]); o[2] = f2bf(v[2]); o[3] = f2bf(v[3]);
    *(s16x4*)(out + i * 4) = o;
  }
}

// ---------------- qkv bias concat ----------------
__global__ void bias_cat(const float* __restrict__ bq, const float* __restrict__ bk,
                         const float* __restrict__ bv, float* __restrict__ out) {
  int i = blockIdx.x * 256 + threadIdx.x;
  if (i < QKVD) out[i] = i < DIM ? bq[i] : (i < 2 * DIM ? bk[i - DIM] : bv[i - 2 * DIM]);
}

// ---------------- gemm4: pipelined MFMA GEMM, 3 blocks/CU ----------------
// C[M,N] = epi(A[M,K] @ Bt[N,K]^T). 128x128 tile, BK=32, 4 waves, 3 LDS
// buffers (16KB each -> 48KB -> 3 blocks/CU), prefetch distance 2, counted
// s_waitcnt vmcnt(4) at tile boundary (never 0 in main loop).
// Swizzle: BK=32 rows are 64B (half a bank window), so XOR at 2-row
// granularity: physical chunk cp holds logical chunk cp^((row>>1)&3).
// Lanes 0-7 then hit 8 distinct 16B slots on every ds_read_b128 (2-way=free).
// KS>1: grid.z splits K; fp32 partials to Cout + z*M*N.
template <bool GELU, bool RES, bool BIAS, bool OUTBF16, int KS, bool XCDSWZ>
__global__ __launch_bounds__(256, 3) void gemm4(
    const short* __restrict__ A, const short* __restrict__ Bt,
    const float* __restrict__ bias, const float* __restrict__ res,
    void* __restrict__ Cout, int N, int Kfull) {
  __shared__ short lds[3][(128 + 128) * 32];  // 3 x 16KB
  const int tid = threadIdx.x, wid = tid >> 6, lane = tid & 63;
  const int l16 = lane & 15, lg = lane >> 4;
  int bx = blockIdx.x, by = blockIdx.y;
  if (XCDSWZ) {  // bijective chunked remap; caller guarantees nwg % 8 == 0
    int gx = gridDim.x, nwg = gx * gridDim.y;
    int flat = by * gx + bx;
    int nf = (flat & 7) * (nwg >> 3) + (flat >> 3);
    bx = nf % gx; by = nf / gx;
  }
  const long m0 = (long)bx * 128, n0 = (long)by * 128;
  const int K = Kfull / KS;
  const int kbase = blockIdx.z * K;
  const int NT = K / 32;
  const int wr = (wid >> 1) * 64, wc = (wid & 1) * 64;

#define STAGE4(t, b)                                                            \
  {                                                                             \
    short* As_ = lds[b];                                                        \
    short* Bs_ = lds[b] + 128 * 32;                                             \
    int kk_ = kbase + (t) * 32;                                                 \
    _Pragma("unroll")                                                           \
    for (int i_ = 0; i_ < 2; i_++) {                                            \
      int ca_ = i_ * 256 + tid;                                                 \
      int row_ = ca_ >> 2, cp_ = ca_ & 3, c_ = cp_ ^ ((row_ >> 1) & 3);         \
      gload_lds16(A + (m0 + row_) * (long)Kfull + kk_ + c_ * 8,                 \
                  As_ + (i_ * 256 + wid * 64) * 8);                             \
    }                                                                           \
    _Pragma("unroll")                                                           \
    for (int i_ = 0; i_ < 2; i_++) {                                            \
      int ca_ = i_ * 256 + tid;                                                 \
      int row_ = ca_ >> 2, cp_ = ca_ & 3, c_ = cp_ ^ ((row_ >> 1) & 3);         \
      int rowb_ = (int)n0 + row_;                                               \
      if (rowb_ > N - 1) rowb_ = N - 1;                                         \
      gload_lds16(Bt + (long)rowb_ * Kfull + kk_ + c_ * 8,                      \
                  Bs_ + (i_ * 256 + wid * 64) * 8);                             \
    }                                                                           \
  }

  f32x4 acc[4][4] = {};
  // prologue: stage tiles 0 and 1 (8 loads), require tile 0 (vmcnt(4))
  STAGE4(0, 0);
  STAGE4(1, 1);
  asm volatile("s_waitcnt vmcnt(4)" ::: "memory");
  __builtin_amdgcn_s_barrier();
  __builtin_amdgcn_sched_barrier(0);

  for (int t = 0; t < NT; t++) {
    const int b = t % 3;
    if (t + 2 < NT) STAGE4(t + 2, (t + 2) % 3);  // buffer free since iter t-1
    const short* As = lds[b];
    const short* Bs = lds[b] + 128 * 32;
    bf16x8 af[4], bfr[4];
#pragma unroll
    for (int m = 0; m < 4; m++) {
      int row = wr + m * 16 + l16;
      af[m] = *(const bf16x8*)((const char*)As + row * 64 + ((lg ^ ((row >> 1) & 3)) * 16));
    }
#pragma unroll
    for (int n = 0; n < 4; n++) {
      int row = wc + n * 16 + l16;
      bfr[n] = *(const bf16x8*)((const char*)Bs + row * 64 + ((lg ^ ((row >> 1) & 3)) * 16));
    }
    __builtin_amdgcn_s_setprio(1);
#pragma unroll
    for (int m = 0; m < 4; m++)
#pragma unroll
      for (int n = 0; n < 4; n++)
        acc[m][n] = __builtin_amdgcn_mfma_f32_16x16x32_bf16(af[m], bfr[n], acc[m][n], 0, 0, 0);
    __builtin_amdgcn_s_setprio(0);
    // boundary: tile t+1 must be resident; tile t+2's 4 loads stay in flight
    if (t + 2 < NT) {
      asm volatile("s_waitcnt vmcnt(4)" ::: "memory");
    } else if (t + 1 < NT) {
      asm volatile("s_waitcnt vmcnt(0)" ::: "memory");
    }
    if (t + 1 < NT) {
      __builtin_amdgcn_s_barrier();
      __builtin_amdgcn_sched_barrier(0);
    }
  }
#undef STAGE4

  const int lr4 = lg * 4;
  if (KS == 1) {
#pragma unroll
    for (int m = 0; m < 4; m++)
#pragma unroll
      for (int n = 0; n < 4; n++)
#pragma unroll
        for (int r = 0; r < 4; r++) {
          long row = m0 + wr + m * 16 + lr4 + r;
          long col = n0 + wc + n * 16 + l16;
          if (col < N) {
            float v = acc[m][n][r];
            if (BIAS) v += bias[col];
            if (GELU) v = 0.5f * v * (1.f + erff(v * 0.70710678118f));
            if (RES) v += res[row * (long)N + col];
            if (OUTBF16) ((short*)Cout)[row * (long)N + col] = f2bf(v);
            else ((float*)Cout)[row * (long)N + col] = v;
          }
        }
  } else {
    long M = (long)gridDim.x * 128;
    float* P = (float*)Cout + (long)blockIdx.z * M * N;
#pragma unroll
    for (int m = 0; m < 4; m++)
#pragma unroll
      for (int n = 0; n < 4; n++)
#pragma unroll
        for (int r = 0; r < 4; r++) {
          long row = m0 + wr + m * 16 + lr4 + r;
          long col = n0 + wc + n * 16 + l16;
          P[row * (long)N + col] = acc[m][n][r];
        }
  }
}

// ---------------- split-K reduce: h += bias + sum partials ----------------
template <int KS>
__global__ void reduce_k(const float* __restrict__ part, const float* __restrict__ bias,
                         float* __restrict__ h, int N, long MN) {
  long i = ((long)blockIdx.x * 256 + threadIdx.x) * 4;
  if (i >= MN) return;
  fl4 s = *(const fl4*)(h + i);
  fl4 b = *(const fl4*)(bias + (int)(i % N));
  s[0] += b[0]; s[1] += b[1]; s[2] += b[2]; s[3] += b[3];
#pragma unroll
  for (int ks = 0; ks < KS; ks++) {
    fl4 p = *(const fl4*)(part + (long)ks * MN + i);
    s[0] += p[0]; s[1] += p[1]; s[2] += p[2]; s[3] += p[3];
  }
  *(fl4*)(h + i) = s;
}

// ---------------- MFMA flash attention, KVBLK=128 (R4, unchanged) ----------------
__global__ __launch_bounds__(256) void attn_mfma(const short* __restrict__ qkv,
                                                 const short* __restrict__ vtg,
                                                 short* __restrict__ Oa) {
  int hh = blockIdx.x, qb = blockIdx.y;
  int q0 = qb * 64;
  int tid = threadIdx.x, wv = tid >> 6, lane = tid & 63;
  int l16 = lane & 15, lg = lane >> 4;
  int hcol = hh * 64;
  __shared__ short Ks[KVB * 64];
  __shared__ short Vt[64 * KVB];
  __shared__ short Pl[4][16 * KVB];

  bf16x8 qf[2];
  {
    const short* qrow = qkv + (long)(q0 + wv * 16 + l16) * QKVD + hcol;
#pragma unroll
    for (int dc = 0; dc < 2; dc++) {
      bf16x8 t = *(const bf16x8*)(qrow + dc * 32 + lg * 8);
#pragma unroll
      for (int j = 0; j < 8; j++) t[j] = f2bf(bf2f(t[j]) * 0.125f);
      qf[dc] = t;
    }
  }
  f32x4 of[4] = {};
  float mrun[4], lrun[4];
#pragma unroll
  for (int r = 0; r < 4; r++) { mrun[r] = -3e38f; lrun[r] = 0.f; }

  int nt = qb / 2 + 1;
  for (int kt = 0; kt < nt; kt++) {
    int k0 = kt * KVB;
    __syncthreads();
#pragma unroll
    for (int i = 0; i < 4; i++) {
      int ca = i * 256 + tid;
      int row = ca >> 3, cp = ca & 7, c = cp ^ (row & 7);
      int ldsoff = (i * 256 + wv * 64) * 8;
      gload_lds16(qkv + (long)(k0 + row) * QKVD + DIM + hcol + c * 8, (short*)Ks + ldsoff);
    }
#pragma unroll
    for (int i = 0; i < 4; i++) {
      int ca = i * 256 + tid;
      int row = ca >> 4, cp = ca & 15, c = cp ^ (row & 7);
      int ldsoff = (i * 256 + wv * 64) * 8;
      gload_lds16(vtg + (long)(hcol + row) * SEQ + k0 + c * 8, (short*)Vt + ldsoff);
    }
    __syncthreads();

    f32x4 sacc[8] = {};
#pragma unroll
    for (int kc = 0; kc < 8; kc++) {
      int row = kc * 16 + l16;
#pragma unroll
      for (int dc = 0; dc < 2; dc++) {
        bf16x8 kf = *(const bf16x8*)((const char*)Ks + row * 128 + (((dc * 4 + lg) ^ (row & 7)) * 16));
        sacc[kc] = __builtin_amdgcn_mfma_f32_16x16x32_bf16(qf[dc], kf, sacc[kc], 0, 0, 0);
      }
    }

    float sv[8][4], pf[8][4];
#pragma unroll
    for (int kc = 0; kc < 8; kc++)
#pragma unroll
      for (int r = 0; r < 4; r++) sv[kc][r] = sacc[kc][r];
    if (kt == nt - 1) {
#pragma unroll
      for (int kc = 0; kc < 8; kc++)
#pragma unroll
        for (int r = 0; r < 4; r++) {
          int kg = k0 + kc * 16 + l16;
          int rg = q0 + wv * 16 + lg * 4 + r;
          if (kg > rg) sv[kc][r] = -3e38f;
        }
    }
    float corr[4];
#pragma unroll
    for (int r = 0; r < 4; r++) {
      float m01 = fmaxf(sv[0][r], sv[1][r]), m23 = fmaxf(sv[2][r], sv[3][r]);
      float m45 = fmaxf(sv[4][r], sv[5][r]), m67 = fmaxf(sv[6][r], sv[7][r]);
      float mt = fmaxf(fmaxf(m01, m23), fmaxf(m45, m67));
#pragma unroll
      for (int o = 8; o >= 1; o >>= 1) mt = fmaxf(mt, __shfl_xor(mt, o));
      float mn = fmaxf(mrun[r], mt);
      corr[r] = __expf(mrun[r] - mn);
      mrun[r] = mn;
      float ps = 0.f;
#pragma unroll
      for (int kc = 0; kc < 8; kc++) {
        float p = __expf(sv[kc][r] - mn);
        pf[kc][r] = p;
        ps += p;
      }
#pragma unroll
      for (int o = 8; o >= 1; o >>= 1) ps += __shfl_xor(ps, o);
      lrun[r] = lrun[r] * corr[r] + ps;
    }
#pragma unroll
    for (int c = 0; c < 4; c++)
#pragma unroll
      for (int r = 0; r < 4; r++) of[c][r] *= corr[r];
#pragma unroll
    for (int kc = 0; kc < 8; kc++)
#pragma unroll
      for (int r = 0; r < 4; r++) {
        int row = lg * 4 + r, col = kc * 16 + l16;
        int chunk = col >> 3;
        *(short*)((char*)Pl[wv] + row * 256 + ((chunk ^ (row & 7)) * 16) + (col & 7) * 2) = f2bf(pf[kc][r]);
      }
    bf16x8 pfr[4];
#pragma unroll
    for (int kc2 = 0; kc2 < 4; kc2++) {
      int cl = kc2 * 4 + lg;
      pfr[kc2] = *(const bf16x8*)((const char*)Pl[wv] + l16 * 256 + ((cl ^ (l16 & 7)) * 16));
    }
#pragma unroll
    for (int c = 0; c < 4; c++)
#pragma unroll
      for (int kc2 = 0; kc2 < 4; kc2++) {
        int vrow = c * 16 + l16;
        int cl = kc2 * 4 + lg;
        bf16x8 vf = *(const bf16x8*)((const char*)Vt + vrow * 256 + ((cl ^ (vrow & 7)) * 16));
        of[c] = __builtin_amdgcn_mfma_f32_16x16x32_bf16(pfr[kc2], vf, of[c], 0, 0, 0);
      }
  }
#pragma unroll
  for (int c = 0; c < 4; c++)
#pragma unroll
    for (int r = 0; r < 4; r++) {
      int rowg = q0 + wv * 16 + lg * 4 + r;
      int colg = hcol + c * 16 + l16;
      Oa[(long)rowg * DIM + colg] = f2bf(of[c][r] / lrun[r]);
    }
}

// ---------------- orchestration ----------------
extern "C" void kernel_launch(void* const* d_in, const int* in_sizes, int n_in,
                              void* d_out, int out_size, void* d_ws, size_t ws_size,
                              hipStream_t stream) {
  const int* ids = (const int*)d_in[0];
  const float* tok = (const float*)d_in[1];
  const float* pos = (const float*)d_in[2];
  const float* Wq = (const float*)d_in[3];
  const float* bq = (const float*)d_in[4];
  const float* Wk = (const float*)d_in[5];
  const float* bk = (const float*)d_in[6];
  const float* Wv = (const float*)d_in[7];
  const float* bv = (const float*)d_in[8];
  const float* Wo = (const float*)d_in[9];
  const float* bo = (const float*)d_in[10];
  const float* W1 = (const float*)d_in[11];
  const float* b1 = (const float*)d_in[12];
  const float* W2 = (const float*)d_in[13];
  const float* b2 = (const float*)d_in[14];
  const float* ln1w = (const float*)d_in[15];
  const float* ln1b = (const float*)d_in[16];
  const float* ln2w = (const float*)d_in[17];
  const float* ln2b = (const float*)d_in[18];
  const float* lnfw = (const float*)d_in[19];
  const float* lnfb = (const float*)d_in[20];
  const float* lmh = (const float*)d_in[21];
  float* out = (float*)d_out;

  char* wsb = (char*)d_ws;
  float* h = (float*)wsb;                           // 8 MB fp32 residual
  short* x = (short*)(wsb + 8388608);               // 4 MB bf16 LN out
  char* big = wsb + 8388608 + 4194304;
  short* qkv  = (short*)big;                        // 12 MB   [S][3072]
  short* a    = (short*)(big + 12582912);           // 4 MB    [S][1024]
  short* vt   = (short*)(big + 16777216);           // 4 MB    [1024][S]
  short* fbuf = (short*)(big + 20971520);           // 16 MB   [S][4096]
  float* pproj = (float*)fbuf;                      // proj partials: 2x8MB
  float* pffn2 = (float*)big;                       // ffn2 partials: 2x8MB
  char* wdyn = big + 37748736;
  short* wqkvT = (short*)wdyn;                      // 6 MB  [3072][1024]
  short* woT   = (short*)(wdyn + 6291456);          // 2 MB  [1024][1024]
  short* w1T   = (short*)(wdyn + 8388608);          // 8 MB  [4096][1024]
  short* w2T   = (short*)(wdyn + 16777216);         // 8 MB  [1024][4096]
  float* bias3 = (float*)(wdyn + 25165824);         // 12 KB
  short* lmhB = (short*)big;                        // 103 MB, reused after layers

  const long MN = (long)SEQ * DIM;

  embed_kernel<<<(SEQ * DIM + 255) / 256, 256, 0, stream>>>(ids, tok, pos, h);

  dim3 gQKV(SEQ / 128, QKVD / 128);                 // 16 x 24 = 384
  dim3 gPROJ(SEQ / 128, DIM / 128, 2);              // 16 x 8 x 2 = 256
  dim3 gFFN1(SEQ / 128, FFN / 128);                 // 16 x 32 = 512
  dim3 gFFN2(SEQ / 128, DIM / 128, 2);              // 16 x 8 x 2 = 256
  dim3 gV(SEQ / 128, (VOCAB + 127) / 128);          // 16 x 393 = 6288

  for (int l = 0; l < NLAYER; l++) {
    TW4 tw;
    tw.src[0] = Wq + (long)l * DIM * DIM; tw.dst[0] = wqkvT;
    tw.src[1] = Wk + (long)l * DIM * DIM; tw.dst[1] = wqkvT + (long)DIM * DIM;
    tw.src[2] = Wv + (long)l * DIM * DIM; tw.dst[2] = wqkvT + (long)2 * DIM * DIM;
    tw.src[3] = Wo + (long)l * DIM * DIM; tw.dst[3] = woT;
    transpose_w4<<<dim3(32, 32, 4), 256, 0, stream>>>(tw);
    transpose_w<<<dim3(128, 32), 256, 0, stream>>>(W1 + (long)l * DIM * FFN, w1T, DIM, FFN);
    transpose_w<<<dim3(32, 128), 256, 0, stream>>>(W2 + (long)l * FFN * DIM, w2T, FFN, DIM);
    bias_cat<<<12, 256, 0, stream>>>(bq + (long)l * DIM, bk + (long)l * DIM, bv + (long)l * DIM, bias3);

    ln_kernel<<<SEQ, 256, 0, stream>>>(h, ln1w + (long)l * DIM, ln1b + (long)l * DIM, x);
    gemm4<false, false, true, true, 1, true><<<gQKV, 256, 0, stream>>>(x, wqkvT, bias3, nullptr, qkv, QKVD, DIM);
    transpose_v<<<dim3(SEQ / 64, DIM / 64), 256, 0, stream>>>(qkv, vt);
    attn_mfma<<<dim3(NHEAD, SEQ / 64), 256, 0, stream>>>(qkv, vt, a);
    gemm4<false, false, false, false, 2, true><<<gPROJ, 256, 0, stream>>>(a, woT, nullptr, nullptr, pproj, DIM, DIM);
    reduce_k<2><<<(int)(MN / 1024), 256, 0, stream>>>(pproj, bo + (long)l * DIM, h, DIM, MN);
    ln_kernel<<<SEQ, 256, 0, stream>>>(h, ln2w + (long)l * DIM, ln2b + (long)l * DIM, x);
    gemm4<true, false, true, true, 1, true><<<gFFN1, 256, 0, stream>>>(x, w1T, b1 + (long)l * FFN, nullptr, fbuf, FFN, DIM);
    gemm4<false, false, false, false, 2, true><<<gFFN2, 256, 0, stream>>>(fbuf, w2T, nullptr, nullptr, pffn2, DIM, FFN);
    reduce_k<2><<<(int)(MN / 1024), 256, 0, stream>>>(pffn2, b2 + (long)l * DIM, h, DIM, MN);
  }

  ln_kernel<<<SEQ, 256, 0, stream>>>(h, lnfw, lnfb, x);
  conv_bf16<<<2048, 256, 0, stream>>>(lmh, lmhB, (long)VOCAB * DIM / 4);
  gemm4<false, false, false, false, 1, true><<<gV, 256, 0, stream>>>(x, lmhB, nullptr, nullptr, out, VOCAB, DIM);
}

// Round 7
// 1149.525 us; speedup vs baseline: 1.0015x; 1.0015x over previous
//
#include <hip/hip_runtime.h>
#include <math.h>
#include <stdint.h>

// GPT fwd, L=4 D=1024 H=16 HS=64 F=4096 V=50257 S=2048.
// Round 7: lm_head on gemm256 = 256x256 tile, BK=64, 8 waves, 2x64KB LDS
// dbuf, 8-phase interleave (C-quadrant per phase), counted vmcnt(2) at
// phases 4/8 only, reg-resident B-frags, ledger-verified stage schedule.
// Layer GEMMs keep R6 gemm4; attention unchanged.

#define SEQ 2048
#define DIM 1024
#define NHEAD 16
#define FFN 4096
#define VOCAB 50257
#define NLAYER 4
#define LNEPS 1e-5f
#define QKVD 3072
#define KVB 128

using bf16x8 = __attribute__((ext_vector_type(8))) short;
using s16x4  = __attribute__((ext_vector_type(4))) short;
using f32x4  = __attribute__((ext_vector_type(4))) float;
using fl4    = __attribute__((ext_vector_type(4))) float;

static __device__ __forceinline__ short f2bf(float f) {
  uint32_t u = __float_as_uint(f);
  u = (u + 0x7fffu + ((u >> 16) & 1u)) >> 16;
  return (short)u;
}
static __device__ __forceinline__ float bf2f(short s) {
  return __uint_as_float(((uint32_t)(uint16_t)s) << 16);
}
static __device__ __forceinline__ void gload_lds16(const void* g, void* l) {
  __builtin_amdgcn_global_load_lds((const __attribute__((address_space(1))) void*)g,
                                   (__attribute__((address_space(3))) void*)l, 16, 0, 0);
}

// ---------------- embedding (fp32 h) ----------------
__global__ void embed_kernel(const int* __restrict__ ids,
                             const float* __restrict__ tok,
                             const float* __restrict__ pos,
                             float* __restrict__ h) {
  int i = blockIdx.x * blockDim.x + threadIdx.x;
  if (i < SEQ * DIM) {
    int s = i / DIM, d = i % DIM;
    h[i] = tok[(long)ids[s] * DIM + d] + pos[i];
  }
}

// ---------------- layernorm: fp32 in -> bf16 out ----------------
__global__ void ln_kernel(const float* __restrict__ x, const float* __restrict__ w,
                          const float* __restrict__ b, short* __restrict__ y) {
  int row = blockIdx.x;
  const float* xr = x + (long)row * DIM;
  short* yr = y + (long)row * DIM;
  int tid = threadIdx.x;
  float v0 = xr[tid], v1 = xr[tid + 256], v2 = xr[tid + 512], v3 = xr[tid + 768];
  __shared__ float red[8];
  float s = v0 + v1 + v2 + v3;
#pragma unroll
  for (int o = 32; o >= 1; o >>= 1) s += __shfl_xor(s, o);
  if ((tid & 63) == 0) red[tid >> 6] = s;
  __syncthreads();
  float mean = (red[0] + red[1] + red[2] + red[3]) * (1.f / DIM);
  float d0 = v0 - mean, d1 = v1 - mean, d2 = v2 - mean, d3 = v3 - mean;
  float q = d0 * d0 + d1 * d1 + d2 * d2 + d3 * d3;
#pragma unroll
  for (int o = 32; o >= 1; o >>= 1) q += __shfl_xor(q, o);
  if ((tid & 63) == 0) red[4 + (tid >> 6)] = q;
  __syncthreads();
  float var = (red[4] + red[5] + red[6] + red[7]) * (1.f / DIM);
  float rstd = rsqrtf(var + LNEPS);
  yr[tid]       = f2bf(d0 * rstd * w[tid] + b[tid]);
  yr[tid + 256] = f2bf(d1 * rstd * w[tid + 256] + b[tid + 256]);
  yr[tid + 512] = f2bf(d2 * rstd * w[tid + 512] + b[tid + 512]);
  yr[tid + 768] = f2bf(d3 * rstd * w[tid + 768] + b[tid + 768]);
}

// ---------------- weight transpose+convert: [K][N] fp32 -> [N][K] bf16 ----------------
__global__ void transpose_w(const float* __restrict__ in, short* __restrict__ out,
                            int K, int N) {
  __shared__ float t[32][33];
  int c0 = blockIdx.x * 32, r0 = blockIdx.y * 32;
  int tx = threadIdx.x & 31, ty = threadIdx.x >> 5;
#pragma unroll
  for (int i = 0; i < 4; i++)
    t[ty + i * 8][tx] = in[(long)(r0 + ty + i * 8) * N + c0 + tx];
  __syncthreads();
#pragma unroll
  for (int i = 0; i < 4; i++)
    out[(long)(c0 + ty + i * 8) * K + r0 + tx] = f2bf(t[tx][ty + i * 8]);
}

// batched 1024x1024 transposes (Wq,Wk,Wv,Wo) in one launch, z picks matrix
struct TW4 { const float* src[4]; short* dst[4]; };
__global__ void transpose_w4(TW4 p) {
  const float* in = p.src[blockIdx.z];
  short* out = p.dst[blockIdx.z];
  __shared__ float t[32][33];
  int c0 = blockIdx.x * 32, r0 = blockIdx.y * 32;
  int tx = threadIdx.x & 31, ty = threadIdx.x >> 5;
#pragma unroll
  for (int i = 0; i < 4; i++)
    t[ty + i * 8][tx] = in[(long)(r0 + ty + i * 8) * DIM + c0 + tx];
  __syncthreads();
#pragma unroll
  for (int i = 0; i < 4; i++)
    out[(long)(c0 + ty + i * 8) * DIM + r0 + tx] = f2bf(t[tx][ty + i * 8]);
}

// ---------------- V transpose: qkv[s][2D+c] -> vt[c][s], b128 both sides ----------------
__global__ void transpose_v(const short* __restrict__ qkv, short* __restrict__ vt) {
  __shared__ short t[64][72];
  int s0 = blockIdx.x * 64, c0 = blockIdx.y * 64;
  int tid = threadIdx.x;
#pragma unroll
  for (int i = 0; i < 2; i++) {
    int ca = i * 256 + tid;
    int row = ca >> 3, cp = ca & 7;
    bf16x8 v = *(const bf16x8*)(qkv + (long)(s0 + row) * QKVD + 2 * DIM + c0 + cp * 8);
    *(bf16x8*)&t[row][cp * 8] = v;
  }
  __syncthreads();
#pragma unroll
  for (int i = 0; i < 2; i++) {
    int ca = i * 256 + tid;
    int crow = ca >> 3, sp = ca & 7;
    s16x4 a, b;
#pragma unroll
    for (int u = 0; u < 4; u++) a[u] = t[sp * 8 + u][crow];
#pragma unroll
    for (int u = 0; u < 4; u++) b[u] = t[sp * 8 + 4 + u][crow];
    bf16x8 o;
#pragma unroll
    for (int u = 0; u < 4; u++) { o[u] = a[u]; o[4 + u] = b[u]; }
    *(bf16x8*)(vt + (long)(c0 + crow) * SEQ + s0 + sp * 8) = o;
  }
}

// ---------------- fp32 -> bf16 convert (lm_head) ----------------
__global__ void conv_bf16(const float* __restrict__ in, short* __restrict__ out, long n4) {
  long i = (long)blockIdx.x * blockDim.x + threadIdx.x;
  long stride = (long)gridDim.x * blockDim.x;
  for (; i < n4; i += stride) {
    fl4 v = *(const fl4*)(in + i * 4);
    s16x4 o;
    o[0] = f2bf(v[0]); o[1] = f2bf(v[1]); o[2] = f2bf(v[2]); o[3] = f2bf(v[3]);
    *(s16x4*)(out + i * 4) = o;
  }
}

// ---------------- qkv bias concat ----------------
__global__ void bias_cat(const float* __restrict__ bq, const float* __restrict__ bk,
                         const float* __restrict__ bv, float* __restrict__ out) {
  int i = blockIdx.x * 256 + threadIdx.x;
  if (i < QKVD) out[i] = i < DIM ? bq[i] : (i < 2 * DIM ? bk[i - DIM] : bv[i - 2 * DIM]);
}

// ---------------- gemm256: 8-phase pipelined MFMA GEMM (lm_head) ----------------
// C[M,N] = A[M,K] @ Bt[N,K]^T, fp32 out. 256x256 tile, BK=64, 8 waves
// (2Mx4N, per-wave 128x64, acc[8][4]). 2 LDS dbufs (64KB each). Each K-tile
// = 4 quadrant phases: {stage 2 gloads || ds_read subtile -> barrier ->
// setprio + 16 MFMA -> barrier}. B-frags reg-resident per tile (read at q0).
// Counted vmcnt(2) only at phase 4/8 boundaries. Stage schedule targets only
// quadrant-dead regions (ledger-verified):
//  P0:A1A3(o) P1:B01(o) P2:B23(o) P3:A0A2(e+2) | vmcnt(2)
//  P4:A1A3(e+2) P5:B01(e+2) P6:B23(e+2) P7:A0A2(o+2) | vmcnt(2)
template <bool XCDSWZ>
__global__ __launch_bounds__(512, 2) void gemm256(
    const short* __restrict__ A, const short* __restrict__ Bt,
    float* __restrict__ C, int N, int K) {
  __shared__ short ldsA[2][256 * 64];  // 64 KB
  __shared__ short ldsB[2][256 * 64];  // 64 KB
  const int tid = threadIdx.x, wid = tid >> 6, lane = tid & 63;
  const int l16 = lane & 15, lg = lane >> 4;
  const int wm = wid >> 2, wn = wid & 3;
  int bx = blockIdx.x, by = blockIdx.y;
  if (XCDSWZ) {  // bijective chunked remap; caller guarantees nwg % 8 == 0
    int gx = gridDim.x, nwg = gx * gridDim.y;
    int flat = by * gx + bx;
    int nf = (flat & 7) * (nwg >> 3) + (flat >> 3);
    bx = nf % gx; by = nf / gx;
  }
  const long m0 = (long)bx * 256, n0 = (long)by * 256;
  const int NT = K / 64;

  // stage one 64-row slab (1 gload/thread = 8KB); LDS dest linear, source
  // chunk pre-swizzled (both-sides XOR, R4-proven conflict-free)
  auto SA = [&](int t, int b, int r0) {
    int row = r0 + wid * 8 + (lane >> 3);
    int c = (lane & 7) ^ (row & 7);
    gload_lds16(A + (m0 + row) * (long)K + t * 64 + c * 8,
                &ldsA[b][(r0 + wid * 8) * 64]);
  };
  auto SB = [&](int t, int b, int r0) {
    int row = r0 + wid * 8 + (lane >> 3);
    int c = (lane & 7) ^ (row & 7);
    int rowb = (int)n0 + row;
    if (rowb > N - 1) rowb = N - 1;
    gload_lds16(Bt + (long)rowb * K + t * 64 + c * 8,
                &ldsB[b][(r0 + wid * 8) * 64]);
  };

  f32x4 acc[8][4] = {};
  bf16x8 bfr[4][2];  // B-frags, loaded at q0, live across the tile's 4 phases

  auto PH = [&](int b, int q) {  // reads -> barrier -> MFMA (caller adds barB)
    bf16x8 af[2][2];
    if (q == 0) {
#pragma unroll
      for (int nf = 0; nf < 4; nf++) {
        int row = wn * 64 + nf * 16 + l16;
#pragma unroll
        for (int ks = 0; ks < 2; ks++)
          bfr[nf][ks] = *(const bf16x8*)((const char*)&ldsB[b][0] + row * 128 +
                                         (((ks * 4 + lg) ^ (row & 7)) * 16));
      }
    }
#pragma unroll
    for (int j = 0; j < 2; j++) {
      int row = wm * 128 + (q * 2 + j) * 16 + l16;
#pragma unroll
      for (int ks = 0; ks < 2; ks++)
        af[j][ks] = *(const bf16x8*)((const char*)&ldsA[b][0] + row * 128 +
                                     (((ks * 4 + lg) ^ (row & 7)) * 16));
    }
    __builtin_amdgcn_s_barrier();
    __builtin_amdgcn_s_setprio(1);
#pragma unroll
    for (int ks = 0; ks < 2; ks++)
#pragma unroll
      for (int j = 0; j < 2; j++)
#pragma unroll
        for (int nf = 0; nf < 4; nf++)
          acc[q * 2 + j][nf] =
              __builtin_amdgcn_mfma_f32_16x16x32_bf16(af[j][ks], bfr[nf][ks],
                                                      acc[q * 2 + j][nf], 0, 0, 0);
    __builtin_amdgcn_s_setprio(0);
  };

  // prologue: tile0 fully (8 loads) + A0,A2 of tile1 -> vmcnt(2) leaves them
  SA(0, 0, 0); SA(0, 0, 64); SA(0, 0, 128); SA(0, 0, 192);
  SB(0, 0, 0); SB(0, 0, 64); SB(0, 0, 128); SB(0, 0, 192);
  SA(1, 1, 0); SA(1, 1, 128);
  asm volatile("s_waitcnt vmcnt(2)" ::: "memory");
  __builtin_amdgcn_s_barrier();

  for (int i = 0; i < NT / 2; i++) {
    const int e = 2 * i, o = e + 1;
    const bool more = (e + 2) < NT;
    // P0: compute e.q0; stage A1,A3 of tile o (dead since prev P7)
    SA(o, 1, 64); SA(o, 1, 192);
    PH(0, 0);
    __builtin_amdgcn_s_barrier();
    // P1: e.q1; stage B0,B1 of o
    SB(o, 1, 0); SB(o, 1, 64);
    PH(0, 1);
    __builtin_amdgcn_s_barrier();
    // P2: e.q2; stage B2,B3 of o
    SB(o, 1, 128); SB(o, 1, 192);
    PH(0, 2);
    __builtin_amdgcn_s_barrier();
    // P3: e.q3; stage A0,A2 of e+2 (buf0 rows 0-63/128-191 dead since P1)
    if (more) { SA(e + 2, 0, 0); SA(e + 2, 0, 128); }
    PH(0, 3);
    if (more) asm volatile("s_waitcnt vmcnt(2)" ::: "memory");
    else      asm volatile("s_waitcnt vmcnt(0)" ::: "memory");
    __builtin_amdgcn_s_barrier();
    // P4: o.q0; stage A1,A3 of e+2 (dead since P3)
    if (more) { SA(e + 2, 0, 64); SA(e + 2, 0, 192); }
    PH(1, 0);
    __builtin_amdgcn_s_barrier();
    // P5: o.q1; stage B0,B1 of e+2 (buf0 B dead since P3)
    if (more) { SB(e + 2, 0, 0); SB(e + 2, 0, 64); }
    PH(1, 1);
    __builtin_amdgcn_s_barrier();
    // P6: o.q2; stage B2,B3 of e+2
    if (more) { SB(e + 2, 0, 128); SB(e + 2, 0, 192); }
    PH(1, 2);
    __builtin_amdgcn_s_barrier();
    // P7: o.q3; stage A0,A2 of o+2 (buf1 rows 0-63/128-191 dead since P5)
    if (more) { SA(e + 3, 1, 0); SA(e + 3, 1, 128); }
    PH(1, 3);
    if (more) {
      asm volatile("s_waitcnt vmcnt(2)" ::: "memory");
      __builtin_amdgcn_s_barrier();
    }
  }

#pragma unroll
  for (int mf = 0; mf < 8; mf++)
#pragma unroll
    for (int nf = 0; nf < 4; nf++)
#pragma unroll
      for (int r = 0; r < 4; r++) {
        long row = m0 + wm * 128 + mf * 16 + lg * 4 + r;
        long col = n0 + wn * 64 + nf * 16 + l16;
        if (col < N) C[row * (long)N + col] = acc[mf][nf][r];
      }
}

// ---------------- gemm4: pipelined MFMA GEMM, 3 blocks/CU (R6, layers) ----------------
template <bool GELU, bool RES, bool BIAS, bool OUTBF16, int KS, bool XCDSWZ>
__global__ __launch_bounds__(256, 3) void gemm4(
    const short* __restrict__ A, const short* __restrict__ Bt,
    const float* __restrict__ bias, const float* __restrict__ res,
    void* __restrict__ Cout, int N, int Kfull) {
  __shared__ short lds[3][(128 + 128) * 32];  // 3 x 16KB
  const int tid = threadIdx.x, wid = tid >> 6, lane = tid & 63;
  const int l16 = lane & 15, lg = lane >> 4;
  int bx = blockIdx.x, by = blockIdx.y;
  if (XCDSWZ) {
    int gx = gridDim.x, nwg = gx * gridDim.y;
    int flat = by * gx + bx;
    int nf = (flat & 7) * (nwg >> 3) + (flat >> 3);
    bx = nf % gx; by = nf / gx;
  }
  const long m0 = (long)bx * 128, n0 = (long)by * 128;
  const int K = Kfull / KS;
  const int kbase = blockIdx.z * K;
  const int NT = K / 32;
  const int wr = (wid >> 1) * 64, wc = (wid & 1) * 64;

#define STAGE4(t, b)                                                            \
  {                                                                             \
    short* As_ = lds[b];                                                        \
    short* Bs_ = lds[b] + 128 * 32;                                             \
    int kk_ = kbase + (t) * 32;                                                 \
    _Pragma("unroll")                                                           \
    for (int i_ = 0; i_ < 2; i_++) {                                            \
      int ca_ = i_ * 256 + tid;                                                 \
      int row_ = ca_ >> 2, cp_ = ca_ & 3, c_ = cp_ ^ ((row_ >> 1) & 3);         \
      gload_lds16(A + (m0 + row_) * (long)Kfull + kk_ + c_ * 8,                 \
                  As_ + (i_ * 256 + wid * 64) * 8);                             \
    }                                                                           \
    _Pragma("unroll")                                                           \
    for (int i_ = 0; i_ < 2; i_++) {                                            \
      int ca_ = i_ * 256 + tid;                                                 \
      int row_ = ca_ >> 2, cp_ = ca_ & 3, c_ = cp_ ^ ((row_ >> 1) & 3);         \
      int rowb_ = (int)n0 + row_;                                               \
      if (rowb_ > N - 1) rowb_ = N - 1;                                         \
      gload_lds16(Bt + (long)rowb_ * Kfull + kk_ + c_ * 8,                      \
                  Bs_ + (i_ * 256 + wid * 64) * 8);                             \
    }                                                                           \
  }

  f32x4 acc[4][4] = {};
  STAGE4(0, 0);
  STAGE4(1, 1);
  asm volatile("s_waitcnt vmcnt(4)" ::: "memory");
  __builtin_amdgcn_s_barrier();
  __builtin_amdgcn_sched_barrier(0);

  for (int t = 0; t < NT; t++) {
    const int b = t % 3;
    if (t + 2 < NT) STAGE4(t + 2, (t + 2) % 3);
    const short* As = lds[b];
    const short* Bs = lds[b] + 128 * 32;
    bf16x8 af[4], bfr[4];
#pragma unroll
    for (int m = 0; m < 4; m++) {
      int row = wr + m * 16 + l16;
      af[m] = *(const bf16x8*)((const char*)As + row * 64 + ((lg ^ ((row >> 1) & 3)) * 16));
    }
#pragma unroll
    for (int n = 0; n < 4; n++) {
      int row = wc + n * 16 + l16;
      bfr[n] = *(const bf16x8*)((const char*)Bs + row * 64 + ((lg ^ ((row >> 1) & 3)) * 16));
    }
    __builtin_amdgcn_s_setprio(1);
#pragma unroll
    for (int m = 0; m < 4; m++)
#pragma unroll
      for (int n = 0; n < 4; n++)
        acc[m][n] = __builtin_amdgcn_mfma_f32_16x16x32_bf16(af[m], bfr[n], acc[m][n], 0, 0, 0);
    __builtin_amdgcn_s_setprio(0);
    if (t + 2 < NT) {
      asm volatile("s_waitcnt vmcnt(4)" ::: "memory");
    } else if (t + 1 < NT) {
      asm volatile("s_waitcnt vmcnt(0)" ::: "memory");
    }
    if (t + 1 < NT) {
      __builtin_amdgcn_s_barrier();
      __builtin_amdgcn_sched_barrier(0);
    }
  }
#undef STAGE4

  const int lr4 = lg * 4;
  if (KS == 1) {
#pragma unroll
    for (int m = 0; m < 4; m++)
#pragma unroll
      for (int n = 0; n < 4; n++)
#pragma unroll
        for (int r = 0; r < 4; r++) {
          long row = m0 + wr + m * 16 + lr4 + r;
          long col = n0 + wc + n * 16 + l16;
          if (col < N) {
            float v = acc[m][n][r];
            if (BIAS) v += bias[col];
            if (GELU) v = 0.5f * v * (1.f + erff(v * 0.70710678118f));
            if (RES) v += res[row * (long)N + col];
            if (OUTBF16) ((short*)Cout)[row * (long)N + col] = f2bf(v);
            else ((float*)Cout)[row * (long)N + col] = v;
          }
        }
  } else {
    long M = (long)gridDim.x * 128;
    float* P = (float*)Cout + (long)blockIdx.z * M * N;
#pragma unroll
    for (int m = 0; m < 4; m++)
#pragma unroll
      for (int n = 0; n < 4; n++)
#pragma unroll
        for (int r = 0; r < 4; r++) {
          long row = m0 + wr + m * 16 + lr4 + r;
          long col = n0 + wc + n * 16 + l16;
          P[row * (long)N + col] = acc[m][n][r];
        }
  }
}

// ---------------- split-K reduce: h += bias + sum partials ----------------
template <int KS>
__global__ void reduce_k(const float* __restrict__ part, const float* __restrict__ bias,
                         float* __restrict__ h, int N, long MN) {
  long i = ((long)blockIdx.x * 256 + threadIdx.x) * 4;
  if (i >= MN) return;
  fl4 s = *(const fl4*)(h + i);
  fl4 b = *(const fl4*)(bias + (int)(i % N));
  s[0] += b[0]; s[1] += b[1]; s[2] += b[2]; s[3] += b[3];
#pragma unroll
  for (int ks = 0; ks < KS; ks++) {
    fl4 p = *(const fl4*)(part + (long)ks * MN + i);
    s[0] += p[0]; s[1] += p[1]; s[2] += p[2]; s[3] += p[3];
  }
  *(fl4*)(h + i) = s;
}

// ---------------- MFMA flash attention, KVBLK=128 (R4, unchanged) ----------------
__global__ __launch_bounds__(256) void attn_mfma(const short* __restrict__ qkv,
                                                 const short* __restrict__ vtg,
                                                 short* __restrict__ Oa) {
  int hh = blockIdx.x, qb = blockIdx.y;
  int q0 = qb * 64;
  int tid = threadIdx.x, wv = tid >> 6, lane = tid & 63;
  int l16 = lane & 15, lg = lane >> 4;
  int hcol = hh * 64;
  __shared__ short Ks[KVB * 64];
  __shared__ short Vt[64 * KVB];
  __shared__ short Pl[4][16 * KVB];

  bf16x8 qf[2];
  {
    const short* qrow = qkv + (long)(q0 + wv * 16 + l16) * QKVD + hcol;
#pragma unroll
    for (int dc = 0; dc < 2; dc++) {
      bf16x8 t = *(const bf16x8*)(qrow + dc * 32 + lg * 8);
#pragma unroll
      for (int j = 0; j < 8; j++) t[j] = f2bf(bf2f(t[j]) * 0.125f);
      qf[dc] = t;
    }
  }
  f32x4 of[4] = {};
  float mrun[4], lrun[4];
#pragma unroll
  for (int r = 0; r < 4; r++) { mrun[r] = -3e38f; lrun[r] = 0.f; }

  int nt = qb / 2 + 1;
  for (int kt = 0; kt < nt; kt++) {
    int k0 = kt * KVB;
    __syncthreads();
#pragma unroll
    for (int i = 0; i < 4; i++) {
      int ca = i * 256 + tid;
      int row = ca >> 3, cp = ca & 7, c = cp ^ (row & 7);
      int ldsoff = (i * 256 + wv * 64) * 8;
      gload_lds16(qkv + (long)(k0 + row) * QKVD + DIM + hcol + c * 8, (short*)Ks + ldsoff);
    }
#pragma unroll
    for (int i = 0; i < 4; i++) {
      int ca = i * 256 + tid;
      int row = ca >> 4, cp = ca & 15, c = cp ^ (row & 7);
      int ldsoff = (i * 256 + wv * 64) * 8;
      gload_lds16(vtg + (long)(hcol + row) * SEQ + k0 + c * 8, (short*)Vt + ldsoff);
    }
    __syncthreads();

    f32x4 sacc[8] = {};
#pragma unroll
    for (int kc = 0; kc < 8; kc++) {
      int row = kc * 16 + l16;
#pragma unroll
      for (int dc = 0; dc < 2; dc++) {
        bf16x8 kf = *(const bf16x8*)((const char*)Ks + row * 128 + (((dc * 4 + lg) ^ (row & 7)) * 16));
        sacc[kc] = __builtin_amdgcn_mfma_f32_16x16x32_bf16(qf[dc], kf, sacc[kc], 0, 0, 0);
      }
    }

    float sv[8][4], pf[8][4];
#pragma unroll
    for (int kc = 0; kc < 8; kc++)
#pragma unroll
      for (int r = 0; r < 4; r++) sv[kc][r] = sacc[kc][r];
    if (kt == nt - 1) {
#pragma unroll
      for (int kc = 0; kc < 8; kc++)
#pragma unroll
        for (int r = 0; r < 4; r++) {
          int kg = k0 + kc * 16 + l16;
          int rg = q0 + wv * 16 + lg * 4 + r;
          if (kg > rg) sv[kc][r] = -3e38f;
        }
    }
    float corr[4];
#pragma unroll
    for (int r = 0; r < 4; r++) {
      float m01 = fmaxf(sv[0][r], sv[1][r]), m23 = fmaxf(sv[2][r], sv[3][r]);
      float m45 = fmaxf(sv[4][r], sv[5][r]), m67 = fmaxf(sv[6][r], sv[7][r]);
      float mt = fmaxf(fmaxf(m01, m23), fmaxf(m45, m67));
#pragma unroll
      for (int o = 8; o >= 1; o >>= 1) mt = fmaxf(mt, __shfl_xor(mt, o));
      float mn = fmaxf(mrun[r], mt);
      corr[r] = __expf(mrun[r] - mn);
      mrun[r] = mn;
      float ps = 0.f;
#pragma unroll
      for (int kc = 0; kc < 8; kc++) {
        float p = __expf(sv[kc][r] - mn);
        pf[kc][r] = p;
        ps += p;
      }
#pragma unroll
      for (int o = 8; o >= 1; o >>= 1) ps += __shfl_xor(ps, o);
      lrun[r] = lrun[r] * corr[r] + ps;
    }
#pragma unroll
    for (int c = 0; c < 4; c++)
#pragma unroll
      for (int r = 0; r < 4; r++) of[c][r] *= corr[r];
#pragma unroll
    for (int kc = 0; kc < 8; kc++)
#pragma unroll
      for (int r = 0; r < 4; r++) {
        int row = lg * 4 + r, col = kc * 16 + l16;
        int chunk = col >> 3;
        *(short*)((char*)Pl[wv] + row * 256 + ((chunk ^ (row & 7)) * 16) + (col & 7) * 2) = f2bf(pf[kc][r]);
      }
    bf16x8 pfr[4];
#pragma unroll
    for (int kc2 = 0; kc2 < 4; kc2++) {
      int cl = kc2 * 4 + lg;
      pfr[kc2] = *(const bf16x8*)((const char*)Pl[wv] + l16 * 256 + ((cl ^ (l16 & 7)) * 16));
    }
#pragma unroll
    for (int c = 0; c < 4; c++)
#pragma unroll
      for (int kc2 = 0; kc2 < 4; kc2++) {
        int vrow = c * 16 + l16;
        int cl = kc2 * 4 + lg;
        bf16x8 vf = *(const bf16x8*)((const char*)Vt + vrow * 256 + ((cl ^ (vrow & 7)) * 16));
        of[c] = __builtin_amdgcn_mfma_f32_16x16x32_bf16(pfr[kc2], vf, of[c], 0, 0, 0);
      }
  }
#pragma unroll
  for (int c = 0; c < 4; c++)
#pragma unroll
    for (int r = 0; r < 4; r++) {
      int rowg = q0 + wv * 16 + lg * 4 + r;
      int colg = hcol + c * 16 + l16;
      Oa[(long)rowg * DIM + colg] = f2bf(of[c][r] / lrun[r]);
    }
}

// ---------------- orchestration ----------------
extern "C" void kernel_launch(void* const* d_in, const int* in_sizes, int n_in,
                              void* d_out, int out_size, void* d_ws, size_t ws_size,
                              hipStream_t stream) {
  const int* ids = (const int*)d_in[0];
  const float* tok = (const float*)d_in[1];
  const float* pos = (const float*)d_in[2];
  const float* Wq = (const float*)d_in[3];
  const float* bq = (const float*)d_in[4];
  const float* Wk = (const float*)d_in[5];
  const float* bk = (const float*)d_in[6];
  const float* Wv = (const float*)d_in[7];
  const float* bv = (const float*)d_in[8];
  const float* Wo = (const float*)d_in[9];
  const float* bo = (const float*)d_in[10];
  const float* W1 = (const float*)d_in[11];
  const float* b1 = (const float*)d_in[12];
  const float* W2 = (const float*)d_in[13];
  const float* b2 = (const float*)d_in[14];
  const float* ln1w = (const float*)d_in[15];
  const float* ln1b = (const float*)d_in[16];
  const float* ln2w = (const float*)d_in[17];
  const float* ln2b = (const float*)d_in[18];
  const float* lnfw = (const float*)d_in[19];
  const float* lnfb = (const float*)d_in[20];
  const float* lmh = (const float*)d_in[21];
  float* out = (float*)d_out;

  char* wsb = (char*)d_ws;
  float* h = (float*)wsb;                           // 8 MB fp32 residual
  short* x = (short*)(wsb + 8388608);               // 4 MB bf16 LN out
  char* big = wsb + 8388608 + 4194304;
  short* qkv  = (short*)big;                        // 12 MB   [S][3072]
  short* a    = (short*)(big + 12582912);           // 4 MB    [S][1024]
  short* vt   = (short*)(big + 16777216);           // 4 MB    [1024][S]
  short* fbuf = (short*)(big + 20971520);           // 16 MB   [S][4096]
  float* pproj = (float*)fbuf;                      // proj partials: 2x8MB
  float* pffn2 = (float*)big;                       // ffn2 partials: 2x8MB
  char* wdyn = big + 37748736;
  short* wqkvT = (short*)wdyn;                      // 6 MB  [3072][1024]
  short* woT   = (short*)(wdyn + 6291456);          // 2 MB  [1024][1024]
  short* w1T   = (short*)(wdyn + 8388608);          // 8 MB  [4096][1024]
  short* w2T   = (short*)(wdyn + 16777216);         // 8 MB  [1024][4096]
  float* bias3 = (float*)(wdyn + 25165824);         // 12 KB
  short* lmhB = (short*)big;                        // 103 MB, reused after layers

  const long MN = (long)SEQ * DIM;

  embed_kernel<<<(SEQ * DIM + 255) / 256, 256, 0, stream>>>(ids, tok, pos, h);

  dim3 gQKV(SEQ / 128, QKVD / 128);                 // 16 x 24 = 384
  dim3 gPROJ(SEQ / 128, DIM / 128, 2);              // 16 x 8 x 2 = 256
  dim3 gFFN1(SEQ / 128, FFN / 128);                 // 16 x 32 = 512
  dim3 gFFN2(SEQ / 128, DIM / 128, 2);              // 16 x 8 x 2 = 256
  dim3 gV(SEQ / 256, (VOCAB + 255) / 256);          // 8 x 197 = 1576 (%8==0)

  for (int l = 0; l < NLAYER; l++) {
    TW4 tw;
    tw.src[0] = Wq + (long)l * DIM * DIM; tw.dst[0] = wqkvT;
    tw.src[1] = Wk + (long)l * DIM * DIM; tw.dst[1] = wqkvT + (long)DIM * DIM;
    tw.src[2] = Wv + (long)l * DIM * DIM; tw.dst[2] = wqkvT + (long)2 * DIM * DIM;
    tw.src[3] = Wo + (long)l * DIM * DIM; tw.dst[3] = woT;
    transpose_w4<<<dim3(32, 32, 4), 256, 0, stream>>>(tw);
    transpose_w<<<dim3(128, 32), 256, 0, stream>>>(W1 + (long)l * DIM * FFN, w1T, DIM, FFN);
    transpose_w<<<dim3(32, 128), 256, 0, stream>>>(W2 + (long)l * FFN * DIM, w2T, FFN, DIM);
    bias_cat<<<12, 256, 0, stream>>>(bq + (long)l * DIM, bk + (long)l * DIM, bv + (long)l * DIM, bias3);

    ln_kernel<<<SEQ, 256, 0, stream>>>(h, ln1w + (long)l * DIM, ln1b + (long)l * DIM, x);
    gemm4<false, false, true, true, 1, true><<<gQKV, 256, 0, stream>>>(x, wqkvT, bias3, nullptr, qkv, QKVD, DIM);
    transpose_v<<<dim3(SEQ / 64, DIM / 64), 256, 0, stream>>>(qkv, vt);
    attn_mfma<<<dim3(NHEAD, SEQ / 64), 256, 0, stream>>>(qkv, vt, a);
    gemm4<false, false, false, false, 2, true><<<gPROJ, 256, 0, stream>>>(a, woT, nullptr, nullptr, pproj, DIM, DIM);
    reduce_k<2><<<(int)(MN / 1024), 256, 0, stream>>>(pproj, bo + (long)l * DIM, h, DIM, MN);
    ln_kernel<<<SEQ, 256, 0, stream>>>(h, ln2w + (long)l * DIM, ln2b + (long)l * DIM, x);
    gemm4<true, false, true, true, 1, true><<<gFFN1, 256, 0, stream>>>(x, w1T, b1 + (long)l * FFN, nullptr, fbuf, FFN, DIM);
    gemm4<false, false, false, false, 2, true><<<gFFN2, 256, 0, stream>>>(fbuf, w2T, nullptr, nullptr, pffn2, DIM, FFN);
    reduce_k<2><<<(int)(MN / 1024), 256, 0, stream>>>(pffn2, b2 + (long)l * DIM, h, DIM, MN);
  }

  ln_kernel<<<SEQ, 256, 0, stream>>>(h, lnfw, lnfb, x);
  conv_bf16<<<2048, 256, 0, stream>>>(lmh, lmhB, (long)VOCAB * DIM / 4);
  gemm256<true><<<gV, 512, 0, stream>>>(x, lmhB, out, VOCAB, DIM);
}

// Round 8
// 1137.993 us; speedup vs baseline: 1.0117x; 1.0101x over previous
//
#include <hip/hip_runtime.h>
#include <math.h>
#include <stdint.h>

// GPT fwd, L=4 D=1024 H=16 HS=64 F=4096 V=50257 S=2048.
// Round 8: attention double-buffered staging (counted sync, 2 blocks/CU),
// gemm_small 64x128 for QKV/proj/FFN2 (grid fills machine), fused
// reduce+LN epilogue, vectorized transposes. lm_head gemm256 unchanged.

#define SEQ 2048
#define DIM 1024
#define NHEAD 16
#define FFN 4096
#define VOCAB 50257
#define NLAYER 4
#define LNEPS 1e-5f
#define QKVD 3072
#define KVB 128

using bf16x8 = __attribute__((ext_vector_type(8))) short;
using s16x4  = __attribute__((ext_vector_type(4))) short;
using f32x4  = __attribute__((ext_vector_type(4))) float;
using fl4    = __attribute__((ext_vector_type(4))) float;

static __device__ __forceinline__ short f2bf(float f) {
  uint32_t u = __float_as_uint(f);
  u = (u + 0x7fffu + ((u >> 16) & 1u)) >> 16;
  return (short)u;
}
static __device__ __forceinline__ float bf2f(short s) {
  return __uint_as_float(((uint32_t)(uint16_t)s) << 16);
}
static __device__ __forceinline__ void gload_lds16(const void* g, void* l) {
  __builtin_amdgcn_global_load_lds((const __attribute__((address_space(1))) void*)g,
                                   (__attribute__((address_space(3))) void*)l, 16, 0, 0);
}

// ---------------- embedding (fp32 h) ----------------
__global__ void embed_kernel(const int* __restrict__ ids,
                             const float* __restrict__ tok,
                             const float* __restrict__ pos,
                             float* __restrict__ h) {
  int i = blockIdx.x * blockDim.x + threadIdx.x;
  if (i < SEQ * DIM) {
    int s = i / DIM, d = i % DIM;
    h[i] = tok[(long)ids[s] * DIM + d] + pos[i];
  }
}

// ---------------- layernorm: fp32 in -> bf16 out (used once, layer0 ln1) ----------------
__global__ void ln_kernel(const float* __restrict__ x, const float* __restrict__ w,
                          const float* __restrict__ b, short* __restrict__ y) {
  int row = blockIdx.x;
  const float* xr = x + (long)row * DIM;
  short* yr = y + (long)row * DIM;
  int tid = threadIdx.x;
  float v0 = xr[tid], v1 = xr[tid + 256], v2 = xr[tid + 512], v3 = xr[tid + 768];
  __shared__ float red[8];
  float s = v0 + v1 + v2 + v3;
#pragma unroll
  for (int o = 32; o >= 1; o >>= 1) s += __shfl_xor(s, o);
  if ((tid & 63) == 0) red[tid >> 6] = s;
  __syncthreads();
  float mean = (red[0] + red[1] + red[2] + red[3]) * (1.f / DIM);
  float d0 = v0 - mean, d1 = v1 - mean, d2 = v2 - mean, d3 = v3 - mean;
  float q = d0 * d0 + d1 * d1 + d2 * d2 + d3 * d3;
#pragma unroll
  for (int o = 32; o >= 1; o >>= 1) q += __shfl_xor(q, o);
  if ((tid & 63) == 0) red[4 + (tid >> 6)] = q;
  __syncthreads();
  float var = (red[4] + red[5] + red[6] + red[7]) * (1.f / DIM);
  float rstd = rsqrtf(var + LNEPS);
  yr[tid]       = f2bf(d0 * rstd * w[tid] + b[tid]);
  yr[tid + 256] = f2bf(d1 * rstd * w[tid + 256] + b[tid + 256]);
  yr[tid + 512] = f2bf(d2 * rstd * w[tid + 512] + b[tid + 512]);
  yr[tid + 768] = f2bf(d3 * rstd * w[tid + 768] + b[tid + 768]);
}

// ---------------- fused: h += bias + part0 + part1; x = LN(h) bf16 ----------------
__global__ void reduce_ln(const float* __restrict__ part, const float* __restrict__ bias,
                          const float* __restrict__ lnw, const float* __restrict__ lnb,
                          float* __restrict__ h, short* __restrict__ x) {
  const long MN = (long)SEQ * DIM;
  int row = blockIdx.x, tid = threadIdx.x;
  long off = (long)row * DIM + tid * 4;
  fl4 hv = *(const fl4*)(h + off);
  fl4 p0 = *(const fl4*)(part + off);
  fl4 p1 = *(const fl4*)(part + MN + off);
  fl4 bv = *(const fl4*)(bias + tid * 4);
  float v[4];
#pragma unroll
  for (int u = 0; u < 4; u++) v[u] = hv[u] + p0[u] + p1[u] + bv[u];
  __shared__ float red[8];
  float s = v[0] + v[1] + v[2] + v[3];
#pragma unroll
  for (int o = 32; o >= 1; o >>= 1) s += __shfl_xor(s, o);
  if ((tid & 63) == 0) red[tid >> 6] = s;
  __syncthreads();
  float mean = (red[0] + red[1] + red[2] + red[3]) * (1.f / DIM);
  float d[4], q = 0.f;
#pragma unroll
  for (int u = 0; u < 4; u++) { d[u] = v[u] - mean; q += d[u] * d[u]; }
#pragma unroll
  for (int o = 32; o >= 1; o >>= 1) q += __shfl_xor(q, o);
  if ((tid & 63) == 0) red[4 + (tid >> 6)] = q;
  fl4 hw; hw[0] = v[0]; hw[1] = v[1]; hw[2] = v[2]; hw[3] = v[3];
  *(fl4*)(h + off) = hw;
  __syncthreads();
  float var = (red[4] + red[5] + red[6] + red[7]) * (1.f / DIM);
  float rstd = rsqrtf(var + LNEPS);
  fl4 w = *(const fl4*)(lnw + tid * 4);
  fl4 bb = *(const fl4*)(lnb + tid * 4);
  s16x4 o;
#pragma unroll
  for (int u = 0; u < 4; u++) o[u] = f2bf(d[u] * rstd * w[u] + bb[u]);
  *(s16x4*)(x + off) = o;
}

// ---------------- transpose+convert [K][N] fp32 -> [N][K] bf16, 64x64 tiles ----------------
__global__ void transpose64(const float* __restrict__ in, short* __restrict__ out,
                            int K, int N) {
  __shared__ float ts[64][65];
  int c0 = blockIdx.x * 64, r0 = blockIdx.y * 64;
  int tid = threadIdx.x;
  int lr = tid >> 4, lc4 = (tid & 15) * 4;
#pragma unroll
  for (int i = 0; i < 4; i++) {
    fl4 v = *(const fl4*)(in + (long)(r0 + lr + i * 16) * N + c0 + lc4);
    ts[lr + i * 16][lc4] = v[0]; ts[lr + i * 16][lc4 + 1] = v[1];
    ts[lr + i * 16][lc4 + 2] = v[2]; ts[lr + i * 16][lc4 + 3] = v[3];
  }
  __syncthreads();
#pragma unroll
  for (int i = 0; i < 2; i++) {
    int oc = (tid >> 3) + i * 32, seg = tid & 7;
    bf16x8 o;
#pragma unroll
    for (int u = 0; u < 8; u++) o[u] = f2bf(ts[seg * 8 + u][oc]);
    *(bf16x8*)(out + (long)(c0 + oc) * K + r0 + seg * 8) = o;
  }
}

// batched square transposes (Wq,Wk,Wv,Wo), z picks matrix
struct TW4 { const float* src[4]; short* dst[4]; };
__global__ void transpose64_b4(TW4 p) {
  const float* in = p.src[blockIdx.z];
  short* out = p.dst[blockIdx.z];
  __shared__ float ts[64][65];
  int c0 = blockIdx.x * 64, r0 = blockIdx.y * 64;
  int tid = threadIdx.x;
  int lr = tid >> 4, lc4 = (tid & 15) * 4;
#pragma unroll
  for (int i = 0; i < 4; i++) {
    fl4 v = *(const fl4*)(in + (long)(r0 + lr + i * 16) * DIM + c0 + lc4);
    ts[lr + i * 16][lc4] = v[0]; ts[lr + i * 16][lc4 + 1] = v[1];
    ts[lr + i * 16][lc4 + 2] = v[2]; ts[lr + i * 16][lc4 + 3] = v[3];
  }
  __syncthreads();
#pragma unroll
  for (int i = 0; i < 2; i++) {
    int oc = (tid >> 3) + i * 32, seg = tid & 7;
    bf16x8 o;
#pragma unroll
    for (int u = 0; u < 8; u++) o[u] = f2bf(ts[seg * 8 + u][oc]);
    *(bf16x8*)(out + (long)(c0 + oc) * DIM + r0 + seg * 8) = o;
  }
}

// ---------------- V transpose: qkv[s][2D+c] -> vt[c][s] ----------------
__global__ void transpose_v(const short* __restrict__ qkv, short* __restrict__ vt) {
  __shared__ short t[64][72];
  int s0 = blockIdx.x * 64, c0 = blockIdx.y * 64;
  int tid = threadIdx.x;
#pragma unroll
  for (int i = 0; i < 2; i++) {
    int ca = i * 256 + tid;
    int row = ca >> 3, cp = ca & 7;
    bf16x8 v = *(const bf16x8*)(qkv + (long)(s0 + row) * QKVD + 2 * DIM + c0 + cp * 8);
    *(bf16x8*)&t[row][cp * 8] = v;
  }
  __syncthreads();
#pragma unroll
  for (int i = 0; i < 2; i++) {
    int ca = i * 256 + tid;
    int crow = ca >> 3, sp = ca & 7;
    bf16x8 o;
#pragma unroll
    for (int u = 0; u < 8; u++) o[u] = t[sp * 8 + u][crow];
    *(bf16x8*)(vt + (long)(c0 + crow) * SEQ + s0 + sp * 8) = o;
  }
}

// ---------------- fp32 -> bf16 convert (lm_head) ----------------
__global__ void conv_bf16(const float* __restrict__ in, short* __restrict__ out, long n4) {
  long i = (long)blockIdx.x * blockDim.x + threadIdx.x;
  long stride = (long)gridDim.x * blockDim.x;
  for (; i < n4; i += stride) {
    fl4 v = *(const fl4*)(in + i * 4);
    s16x4 o;
    o[0] = f2bf(v[0]); o[1] = f2bf(v[1]); o[2] = f2bf(v[2]); o[3] = f2bf(v[3]);
    *(s16x4*)(out + i * 4) = o;
  }
}

// ---------------- qkv bias concat ----------------
__global__ void bias_cat(const float* __restrict__ bq, const float* __restrict__ bk,
                         const float* __restrict__ bv, float* __restrict__ out) {
  int i = blockIdx.x * 256 + threadIdx.x;
  if (i < QKVD) out[i] = i < DIM ? bq[i] : (i < 2 * DIM ? bk[i - DIM] : bv[i - 2 * DIM]);
}

// ---------------- gemm_small: 64x128 tile, BK=32, 4 waves, 4+ blocks/CU ----------------
// Same pipeline skeleton as gemm4 (3 buffers, distance-2, counted vmcnt(3)).
// Wave grid 2m x 2n, per-wave 32x64, acc[2][4]. N must be a multiple of 128.
template <bool GELU, bool BIAS, bool OUTBF16, int KS, bool XCDSWZ>
__global__ __launch_bounds__(256, 4) void gemm_small(
    const short* __restrict__ A, const short* __restrict__ Bt,
    const float* __restrict__ bias, void* __restrict__ Cout, int N, int Kfull) {
  __shared__ short lds[3][(64 + 128) * 32];  // 3 x 12KB
  const int tid = threadIdx.x, wid = tid >> 6, lane = tid & 63;
  const int l16 = lane & 15, lg = lane >> 4;
  int bx = blockIdx.x, by = blockIdx.y;
  if (XCDSWZ) {
    int gx = gridDim.x, nwg = gx * gridDim.y;
    int flat = by * gx + bx;
    int nf = (flat & 7) * (nwg >> 3) + (flat >> 3);
    bx = nf % gx; by = nf / gx;
  }
  const long m0 = (long)bx * 64, n0 = (long)by * 128;
  const int K = Kfull / KS;
  const int kbase = blockIdx.z * K;
  const int NT = K / 32;
  const int wm = wid >> 1, wn = wid & 1;

#define STG(t, b)                                                               \
  {                                                                             \
    short* As_ = lds[b];                                                        \
    short* Bs_ = lds[b] + 64 * 32;                                              \
    int kk_ = kbase + (t) * 32;                                                 \
    {                                                                           \
      int row_ = tid >> 2, cp_ = tid & 3, c_ = cp_ ^ ((row_ >> 1) & 3);         \
      gload_lds16(A + (m0 + row_) * (long)Kfull + kk_ + c_ * 8,                 \
                  As_ + (wid * 64) * 8);                                        \
    }                                                                           \
    _Pragma("unroll")                                                           \
    for (int i_ = 0; i_ < 2; i_++) {                                            \
      int ca_ = i_ * 256 + tid;                                                 \
      int row_ = ca_ >> 2, cp_ = ca_ & 3, c_ = cp_ ^ ((row_ >> 1) & 3);         \
      gload_lds16(Bt + (long)(n0 + row_) * Kfull + kk_ + c_ * 8,                \
                  Bs_ + (i_ * 256 + wid * 64) * 8);                             \
    }                                                                           \
  }

  f32x4 acc[2][4] = {};
  STG(0, 0);
  STG(1, 1);
  asm volatile("s_waitcnt vmcnt(3)" ::: "memory");
  __builtin_amdgcn_s_barrier();
  __builtin_amdgcn_sched_barrier(0);

  for (int t = 0; t < NT; t++) {
    const int b = t % 3;
    if (t + 2 < NT) STG(t + 2, (t + 2) % 3);
    const short* As = lds[b];
    const short* Bs = lds[b] + 64 * 32;
    bf16x8 af[2], bfr[4];
#pragma unroll
    for (int m = 0; m < 2; m++) {
      int row = wm * 32 + m * 16 + l16;
      af[m] = *(const bf16x8*)((const char*)As + row * 64 + ((lg ^ ((row >> 1) & 3)) * 16));
    }
#pragma unroll
    for (int n = 0; n < 4; n++) {
      int row = wn * 64 + n * 16 + l16;
      bfr[n] = *(const bf16x8*)((const char*)Bs + row * 64 + ((lg ^ ((row >> 1) & 3)) * 16));
    }
    __builtin_amdgcn_s_setprio(1);
#pragma unroll
    for (int m = 0; m < 2; m++)
#pragma unroll
      for (int n = 0; n < 4; n++)
        acc[m][n] = __builtin_amdgcn_mfma_f32_16x16x32_bf16(af[m], bfr[n], acc[m][n], 0, 0, 0);
    __builtin_amdgcn_s_setprio(0);
    if (t + 2 < NT) {
      asm volatile("s_waitcnt vmcnt(3)" ::: "memory");
    } else if (t + 1 < NT) {
      asm volatile("s_waitcnt vmcnt(0)" ::: "memory");
    }
    if (t + 1 < NT) {
      __builtin_amdgcn_s_barrier();
      __builtin_amdgcn_sched_barrier(0);
    }
  }
#undef STG

  const int lr4 = lg * 4;
  if (KS == 1) {
#pragma unroll
    for (int m = 0; m < 2; m++)
#pragma unroll
      for (int n = 0; n < 4; n++)
#pragma unroll
        for (int r = 0; r < 4; r++) {
          long row = m0 + wm * 32 + m * 16 + lr4 + r;
          long col = n0 + wn * 64 + n * 16 + l16;
          float v = acc[m][n][r];
          if (BIAS) v += bias[col];
          if (GELU) v = 0.5f * v * (1.f + erff(v * 0.70710678118f));
          if (OUTBF16) ((short*)Cout)[row * (long)N + col] = f2bf(v);
          else ((float*)Cout)[row * (long)N + col] = v;
        }
  } else {
    long M = (long)gridDim.x * 64;
    float* P = (float*)Cout + (long)blockIdx.z * M * N;
#pragma unroll
    for (int m = 0; m < 2; m++)
#pragma unroll
      for (int n = 0; n < 4; n++)
#pragma unroll
        for (int r = 0; r < 4; r++) {
          long row = m0 + wm * 32 + m * 16 + lr4 + r;
          long col = n0 + wn * 64 + n * 16 + l16;
          P[row * (long)N + col] = acc[m][n][r];
        }
  }
}

// ---------------- gemm4: 128x128, BK=32, 3 blocks/CU (FFN1) ----------------
template <bool GELU, bool BIAS, bool OUTBF16, bool XCDSWZ>
__global__ __launch_bounds__(256, 3) void gemm4(
    const short* __restrict__ A, const short* __restrict__ Bt,
    const float* __restrict__ bias, void* __restrict__ Cout, int N, int Kfull) {
  __shared__ short lds[3][(128 + 128) * 32];  // 3 x 16KB
  const int tid = threadIdx.x, wid = tid >> 6, lane = tid & 63;
  const int l16 = lane & 15, lg = lane >> 4;
  int bx = blockIdx.x, by = blockIdx.y;
  if (XCDSWZ) {
    int gx = gridDim.x, nwg = gx * gridDim.y;
    int flat = by * gx + bx;
    int nf = (flat & 7) * (nwg >> 3) + (flat >> 3);
    bx = nf % gx; by = nf / gx;
  }
  const long m0 = (long)bx * 128, n0 = (long)by * 128;
  const int NT = Kfull / 32;
  const int wr = (wid >> 1) * 64, wc = (wid & 1) * 64;

#define STAGE4(t, b)                                                            \
  {                                                                             \
    short* As_ = lds[b];                                                        \
    short* Bs_ = lds[b] + 128 * 32;                                             \
    int kk_ = (t) * 32;                                                         \
    _Pragma("unroll")                                                           \
    for (int i_ = 0; i_ < 2; i_++) {                                            \
      int ca_ = i_ * 256 + tid;                                                 \
      int row_ = ca_ >> 2, cp_ = ca_ & 3, c_ = cp_ ^ ((row_ >> 1) & 3);         \
      gload_lds16(A + (m0 + row_) * (long)Kfull + kk_ + c_ * 8,                 \
                  As_ + (i_ * 256 + wid * 64) * 8);                             \
    }                                                                           \
    _Pragma("unroll")                                                           \
    for (int i_ = 0; i_ < 2; i_++) {                                            \
      int ca_ = i_ * 256 + tid;                                                 \
      int row_ = ca_ >> 2, cp_ = ca_ & 3, c_ = cp_ ^ ((row_ >> 1) & 3);         \
      gload_lds16(Bt + (long)(n0 + row_) * Kfull + kk_ + c_ * 8,                \
                  Bs_ + (i_ * 256 + wid * 64) * 8);                             \
    }                                                                           \
  }

  f32x4 acc[4][4] = {};
  STAGE4(0, 0);
  STAGE4(1, 1);
  asm volatile("s_waitcnt vmcnt(4)" ::: "memory");
  __builtin_amdgcn_s_barrier();
  __builtin_amdgcn_sched_barrier(0);

  for (int t = 0; t < NT; t++) {
    const int b = t % 3;
    if (t + 2 < NT) STAGE4(t + 2, (t + 2) % 3);
    const short* As = lds[b];
    const short* Bs = lds[b] + 128 * 32;
    bf16x8 af[4], bfr[4];
#pragma unroll
    for (int m = 0; m < 4; m++) {
      int row = wr + m * 16 + l16;
      af[m] = *(const bf16x8*)((const char*)As + row * 64 + ((lg ^ ((row >> 1) & 3)) * 16));
    }
#pragma unroll
    for (int n = 0; n < 4; n++) {
      int row = wc + n * 16 + l16;
      bfr[n] = *(const bf16x8*)((const char*)Bs + row * 64 + ((lg ^ ((row >> 1) & 3)) * 16));
    }
    __builtin_amdgcn_s_setprio(1);
#pragma unroll
    for (int m = 0; m < 4; m++)
#pragma unroll
      for (int n = 0; n < 4; n++)
        acc[m][n] = __builtin_amdgcn_mfma_f32_16x16x32_bf16(af[m], bfr[n], acc[m][n], 0, 0, 0);
    __builtin_amdgcn_s_setprio(0);
    if (t + 2 < NT) {
      asm volatile("s_waitcnt vmcnt(4)" ::: "memory");
    } else if (t + 1 < NT) {
      asm volatile("s_waitcnt vmcnt(0)" ::: "memory");
    }
    if (t + 1 < NT) {
      __builtin_amdgcn_s_barrier();
      __builtin_amdgcn_sched_barrier(0);
    }
  }
#undef STAGE4

  const int lr4 = lg * 4;
#pragma unroll
  for (int m = 0; m < 4; m++)
#pragma unroll
    for (int n = 0; n < 4; n++)
#pragma unroll
      for (int r = 0; r < 4; r++) {
        long row = m0 + wr + m * 16 + lr4 + r;
        long col = n0 + wc + n * 16 + l16;
        float v = acc[m][n][r];
        if (BIAS) v += bias[col];
        if (GELU) v = 0.5f * v * (1.f + erff(v * 0.70710678118f));
        if (OUTBF16) ((short*)Cout)[row * (long)N + col] = f2bf(v);
        else ((float*)Cout)[row * (long)N + col] = v;
      }
}

// ---------------- gemm256: 8-phase pipelined MFMA GEMM (lm_head, R7) ----------------
template <bool XCDSWZ>
__global__ __launch_bounds__(512, 2) void gemm256(
    const short* __restrict__ A, const short* __restrict__ Bt,
    float* __restrict__ C, int N, int K) {
  __shared__ short ldsA[2][256 * 64];
  __shared__ short ldsB[2][256 * 64];
  const int tid = threadIdx.x, wid = tid >> 6, lane = tid & 63;
  const int l16 = lane & 15, lg = lane >> 4;
  const int wm = wid >> 2, wn = wid & 3;
  int bx = blockIdx.x, by = blockIdx.y;
  if (XCDSWZ) {
    int gx = gridDim.x, nwg = gx * gridDim.y;
    int flat = by * gx + bx;
    int nf = (flat & 7) * (nwg >> 3) + (flat >> 3);
    bx = nf % gx; by = nf / gx;
  }
  const long m0 = (long)bx * 256, n0 = (long)by * 256;
  const int NT = K / 64;

  auto SA = [&](int t, int b, int r0) {
    int row = r0 + wid * 8 + (lane >> 3);
    int c = (lane & 7) ^ (row & 7);
    gload_lds16(A + (m0 + row) * (long)K + t * 64 + c * 8,
                &ldsA[b][(r0 + wid * 8) * 64]);
  };
  auto SB = [&](int t, int b, int r0) {
    int row = r0 + wid * 8 + (lane >> 3);
    int c = (lane & 7) ^ (row & 7);
    int rowb = (int)n0 + row;
    if (rowb > N - 1) rowb = N - 1;
    gload_lds16(Bt + (long)rowb * K + t * 64 + c * 8,
                &ldsB[b][(r0 + wid * 8) * 64]);
  };

  f32x4 acc[8][4] = {};
  bf16x8 bfr[4][2];

  auto PH = [&](int b, int q) {
    bf16x8 af[2][2];
    if (q == 0) {
#pragma unroll
      for (int nf = 0; nf < 4; nf++) {
        int row = wn * 64 + nf * 16 + l16;
#pragma unroll
        for (int ks = 0; ks < 2; ks++)
          bfr[nf][ks] = *(const bf16x8*)((const char*)&ldsB[b][0] + row * 128 +
                                         (((ks * 4 + lg) ^ (row & 7)) * 16));
      }
    }
#pragma unroll
    for (int j = 0; j < 2; j++) {
      int row = wm * 128 + (q * 2 + j) * 16 + l16;
#pragma unroll
      for (int ks = 0; ks < 2; ks++)
        af[j][ks] = *(const bf16x8*)((const char*)&ldsA[b][0] + row * 128 +
                                     (((ks * 4 + lg) ^ (row & 7)) * 16));
    }
    __builtin_amdgcn_s_barrier();
    __builtin_amdgcn_s_setprio(1);
#pragma unroll
    for (int ks = 0; ks < 2; ks++)
#pragma unroll
      for (int j = 0; j < 2; j++)
#pragma unroll
        for (int nf = 0; nf < 4; nf++)
          acc[q * 2 + j][nf] =
              __builtin_amdgcn_mfma_f32_16x16x32_bf16(af[j][ks], bfr[nf][ks],
                                                      acc[q * 2 + j][nf], 0, 0, 0);
    __builtin_amdgcn_s_setprio(0);
  };

  SA(0, 0, 0); SA(0, 0, 64); SA(0, 0, 128); SA(0, 0, 192);
  SB(0, 0, 0); SB(0, 0, 64); SB(0, 0, 128); SB(0, 0, 192);
  SA(1, 1, 0); SA(1, 1, 128);
  asm volatile("s_waitcnt vmcnt(2)" ::: "memory");
  __builtin_amdgcn_s_barrier();

  for (int i = 0; i < NT / 2; i++) {
    const int e = 2 * i, o = e + 1;
    const bool more = (e + 2) < NT;
    SA(o, 1, 64); SA(o, 1, 192);
    PH(0, 0);
    __builtin_amdgcn_s_barrier();
    SB(o, 1, 0); SB(o, 1, 64);
    PH(0, 1);
    __builtin_amdgcn_s_barrier();
    SB(o, 1, 128); SB(o, 1, 192);
    PH(0, 2);
    __builtin_amdgcn_s_barrier();
    if (more) { SA(e + 2, 0, 0); SA(e + 2, 0, 128); }
    PH(0, 3);
    if (more) asm volatile("s_waitcnt vmcnt(2)" ::: "memory");
    else      asm volatile("s_waitcnt vmcnt(0)" ::: "memory");
    __builtin_amdgcn_s_barrier();
    if (more) { SA(e + 2, 0, 64); SA(e + 2, 0, 192); }
    PH(1, 0);
    __builtin_amdgcn_s_barrier();
    if (more) { SB(e + 2, 0, 0); SB(e + 2, 0, 64); }
    PH(1, 1);
    __builtin_amdgcn_s_barrier();
    if (more) { SB(e + 2, 0, 128); SB(e + 2, 0, 192); }
    PH(1, 2);
    __builtin_amdgcn_s_barrier();
    if (more) { SA(e + 3, 1, 0); SA(e + 3, 1, 128); }
    PH(1, 3);
    if (more) {
      asm volatile("s_waitcnt vmcnt(2)" ::: "memory");
      __builtin_amdgcn_s_barrier();
    }
  }

#pragma unroll
  for (int mf = 0; mf < 8; mf++)
#pragma unroll
    for (int nf = 0; nf < 4; nf++)
#pragma unroll
      for (int r = 0; r < 4; r++) {
        long row = m0 + wm * 128 + mf * 16 + lg * 4 + r;
        long col = n0 + wn * 64 + nf * 16 + l16;
        if (col < N) C[row * (long)N + col] = acc[mf][nf][r];
      }
}

// ---------------- MFMA flash attention, KVBLK=128, double-buffered staging ----------------
// 2 blocks/CU (80KB LDS). Stage tile t+1 before computing tile t; one
// vmcnt(0)+barrier per tile placed AFTER compute so HBM latency hides.
__global__ __launch_bounds__(256) void attn_mfma(const short* __restrict__ qkv,
                                                 const short* __restrict__ vtg,
                                                 short* __restrict__ Oa) {
  int hh = blockIdx.x, qb = blockIdx.y;
  int q0 = qb * 64;
  int tid = threadIdx.x, wv = tid >> 6, lane = tid & 63;
  int l16 = lane & 15, lg = lane >> 4;
  int hcol = hh * 64;
  __shared__ short Ks[2][KVB * 64];   // 2 x 16KB
  __shared__ short Vt[2][64 * KVB];   // 2 x 16KB
  __shared__ short Pl[4][16 * KVB];   // 16KB (per-wave)

  bf16x8 qf[2];
  {
    const short* qrow = qkv + (long)(q0 + wv * 16 + l16) * QKVD + hcol;
#pragma unroll
    for (int dc = 0; dc < 2; dc++) {
      bf16x8 t = *(const bf16x8*)(qrow + dc * 32 + lg * 8);
#pragma unroll
      for (int j = 0; j < 8; j++) t[j] = f2bf(bf2f(t[j]) * 0.125f);
      qf[dc] = t;
    }
  }
  f32x4 of[4] = {};
  float mrun[4], lrun[4];
#pragma unroll
  for (int r = 0; r < 4; r++) { mrun[r] = -3e38f; lrun[r] = 0.f; }

#define STAGEKV(kt_, b_)                                                        \
  {                                                                             \
    int k0_ = (kt_) * KVB;                                                      \
    _Pragma("unroll")                                                           \
    for (int i = 0; i < 4; i++) {                                               \
      int ca = i * 256 + tid;                                                   \
      int row = ca >> 3, cp = ca & 7, c = cp ^ (row & 7);                       \
      gload_lds16(qkv + (long)(k0_ + row) * QKVD + DIM + hcol + c * 8,          \
                  (short*)Ks[b_] + (i * 256 + wv * 64) * 8);                    \
    }                                                                           \
    _Pragma("unroll")                                                           \
    for (int i = 0; i < 4; i++) {                                               \
      int ca = i * 256 + tid;                                                   \
      int row = ca >> 4, cp = ca & 15, c = cp ^ (row & 7);                      \
      gload_lds16(vtg + (long)(hcol + row) * SEQ + k0_ + c * 8,                 \
                  (short*)Vt[b_] + (i * 256 + wv * 64) * 8);                    \
    }                                                                           \
  }

  int nt = qb / 2 + 1;
  STAGEKV(0, 0);
  asm volatile("s_waitcnt vmcnt(0)" ::: "memory");
  __builtin_amdgcn_s_barrier();

  for (int kt = 0; kt < nt; kt++) {
    const int cur = kt & 1;
    if (kt + 1 < nt) STAGEKV(kt + 1, cur ^ 1);
    int k0 = kt * KVB;

    f32x4 sacc[8] = {};
#pragma unroll
    for (int kc = 0; kc < 8; kc++) {
      int row = kc * 16 + l16;
#pragma unroll
      for (int dc = 0; dc < 2; dc++) {
        bf16x8 kf = *(const bf16x8*)((const char*)Ks[cur] + row * 128 + (((dc * 4 + lg) ^ (row & 7)) * 16));
        sacc[kc] = __builtin_amdgcn_mfma_f32_16x16x32_bf16(qf[dc], kf, sacc[kc], 0, 0, 0);
      }
    }

    float sv[8][4], pf[8][4];
#pragma unroll
    for (int kc = 0; kc < 8; kc++)
#pragma unroll
      for (int r = 0; r < 4; r++) sv[kc][r] = sacc[kc][r];
    if (kt == nt - 1) {
#pragma unroll
      for (int kc = 0; kc < 8; kc++)
#pragma unroll
        for (int r = 0; r < 4; r++) {
          int kg = k0 + kc * 16 + l16;
          int rg = q0 + wv * 16 + lg * 4 + r;
          if (kg > rg) sv[kc][r] = -3e38f;
        }
    }
    float corr[4];
#pragma unroll
    for (int r = 0; r < 4; r++) {
      float m01 = fmaxf(sv[0][r], sv[1][r]), m23 = fmaxf(sv[2][r], sv[3][r]);
      float m45 = fmaxf(sv[4][r], sv[5][r]), m67 = fmaxf(sv[6][r], sv[7][r]);
      float mt = fmaxf(fmaxf(m01, m23), fmaxf(m45, m67));
#pragma unroll
      for (int o = 8; o >= 1; o >>= 1) mt = fmaxf(mt, __shfl_xor(mt, o));
      float mn = fmaxf(mrun[r], mt);
      corr[r] = __expf(mrun[r] - mn);
      mrun[r] = mn;
      float ps = 0.f;
#pragma unroll
      for (int kc = 0; kc < 8; kc++) {
        float p = __expf(sv[kc][r] - mn);
        pf[kc][r] = p;
        ps += p;
      }
#pragma unroll
      for (int o = 8; o >= 1; o >>= 1) ps += __shfl_xor(ps, o);
      lrun[r] = lrun[r] * corr[r] + ps;
    }
#pragma unroll
    for (int c = 0; c < 4; c++)
#pragma unroll
      for (int r = 0; r < 4; r++) of[c][r] *= corr[r];
#pragma unroll
    for (int kc = 0; kc < 8; kc++)
#pragma unroll
      for (int r = 0; r < 4; r++) {
        int row = lg * 4 + r, col = kc * 16 + l16;
        int chunk = col >> 3;
        *(short*)((char*)Pl[wv] + row * 256 + ((chunk ^ (row & 7)) * 16) + (col & 7) * 2) = f2bf(pf[kc][r]);
      }
    bf16x8 pfr[4];
#pragma unroll
    for (int kc2 = 0; kc2 < 4; kc2++) {
      int cl = kc2 * 4 + lg;
      pfr[kc2] = *(const bf16x8*)((const char*)Pl[wv] + l16 * 256 + ((cl ^ (l16 & 7)) * 16));
    }
#pragma unroll
    for (int c = 0; c < 4; c++)
#pragma unroll
      for (int kc2 = 0; kc2 < 4; kc2++) {
        int vrow = c * 16 + l16;
        int cl = kc2 * 4 + lg;
        bf16x8 vf = *(const bf16x8*)((const char*)Vt[cur] + vrow * 256 + ((cl ^ (vrow & 7)) * 16));
        of[c] = __builtin_amdgcn_mfma_f32_16x16x32_bf16(pfr[kc2], vf, of[c], 0, 0, 0);
      }
    if (kt + 1 < nt) {
      asm volatile("s_waitcnt vmcnt(0)" ::: "memory");
      __builtin_amdgcn_s_barrier();
      __builtin_amdgcn_sched_barrier(0);
    }
  }
#undef STAGEKV
#pragma unroll
  for (int c = 0; c < 4; c++)
#pragma unroll
    for (int r = 0; r < 4; r++) {
      int rowg = q0 + wv * 16 + lg * 4 + r;
      int colg = hcol + c * 16 + l16;
      Oa[(long)rowg * DIM + colg] = f2bf(of[c][r] / lrun[r]);
    }
}

// ---------------- orchestration ----------------
extern "C" void kernel_launch(void* const* d_in, const int* in_sizes, int n_in,
                              void* d_out, int out_size, void* d_ws, size_t ws_size,
                              hipStream_t stream) {
  const int* ids = (const int*)d_in[0];
  const float* tok = (const float*)d_in[1];
  const float* pos = (const float*)d_in[2];
  const float* Wq = (const float*)d_in[3];
  const float* bq = (const float*)d_in[4];
  const float* Wk = (const float*)d_in[5];
  const float* bk = (const float*)d_in[6];
  const float* Wv = (const float*)d_in[7];
  const float* bv = (const float*)d_in[8];
  const float* Wo = (const float*)d_in[9];
  const float* bo = (const float*)d_in[10];
  const float* W1 = (const float*)d_in[11];
  const float* b1 = (const float*)d_in[12];
  const float* W2 = (const float*)d_in[13];
  const float* b2 = (const float*)d_in[14];
  const float* ln1w = (const float*)d_in[15];
  const float* ln1b = (const float*)d_in[16];
  const float* ln2w = (const float*)d_in[17];
  const float* ln2b = (const float*)d_in[18];
  const float* lnfw = (const float*)d_in[19];
  const float* lnfb = (const float*)d_in[20];
  const float* lmh = (const float*)d_in[21];
  float* out = (float*)d_out;

  char* wsb = (char*)d_ws;
  float* h = (float*)wsb;                           // 8 MB fp32 residual
  short* x = (short*)(wsb + 8388608);               // 4 MB bf16 LN out
  char* big = wsb + 8388608 + 4194304;
  short* qkv  = (short*)big;                        // 12 MB   [S][3072]
  short* a    = (short*)(big + 12582912);           // 4 MB    [S][1024]
  short* vt   = (short*)(big + 16777216);           // 4 MB    [1024][S]
  short* fbuf = (short*)(big + 20971520);           // 16 MB   [S][4096]
  float* pproj = (float*)fbuf;                      // proj partials: 2x8MB
  float* pffn2 = (float*)big;                       // ffn2 partials: 2x8MB (qkv+a free)
  char* wdyn = big + 37748736;
  short* wqkvT = (short*)wdyn;                      // 6 MB  [3072][1024]
  short* woT   = (short*)(wdyn + 6291456);          // 2 MB  [1024][1024]
  short* w1T   = (short*)(wdyn + 8388608);          // 8 MB  [4096][1024]
  short* w2T   = (short*)(wdyn + 16777216);         // 8 MB  [1024][4096]
  float* bias3 = (float*)(wdyn + 25165824);         // 12 KB
  short* lmhB = (short*)big;                        // 103 MB, reused after layers

  embed_kernel<<<(SEQ * DIM + 255) / 256, 256, 0, stream>>>(ids, tok, pos, h);
  ln_kernel<<<SEQ, 256, 0, stream>>>(h, ln1w, ln1b, x);  // layer 0 ln1

  dim3 gQKV(SEQ / 64, QKVD / 128);                  // 32 x 24 = 768
  dim3 gPROJ(SEQ / 64, DIM / 128, 2);               // 32 x 8 x 2 = 512
  dim3 gFFN1(SEQ / 128, FFN / 128);                 // 16 x 32 = 512
  dim3 gFFN2(SEQ / 64, DIM / 128, 2);               // 32 x 8 x 2 = 512
  dim3 gV(SEQ / 256, (VOCAB + 255) / 256);          // 8 x 197 = 1576 (%8==0)

  for (int l = 0; l < NLAYER; l++) {
    TW4 tw;
    tw.src[0] = Wq + (long)l * DIM * DIM; tw.dst[0] = wqkvT;
    tw.src[1] = Wk + (long)l * DIM * DIM; tw.dst[1] = wqkvT + (long)DIM * DIM;
    tw.src[2] = Wv + (long)l * DIM * DIM; tw.dst[2] = wqkvT + (long)2 * DIM * DIM;
    tw.src[3] = Wo + (long)l * DIM * DIM; tw.dst[3] = woT;
    transpose64_b4<<<dim3(16, 16, 4), 256, 0, stream>>>(tw);
    transpose64<<<dim3(64, 16), 256, 0, stream>>>(W1 + (long)l * DIM * FFN, w1T, DIM, FFN);
    transpose64<<<dim3(16, 64), 256, 0, stream>>>(W2 + (long)l * FFN * DIM, w2T, FFN, DIM);
    bias_cat<<<12, 256, 0, stream>>>(bq + (long)l * DIM, bk + (long)l * DIM, bv + (long)l * DIM, bias3);

    gemm_small<false, true, true, 1, true><<<gQKV, 256, 0, stream>>>(x, wqkvT, bias3, qkv, QKVD, DIM);
    transpose_v<<<dim3(SEQ / 64, DIM / 64), 256, 0, stream>>>(qkv, vt);
    attn_mfma<<<dim3(NHEAD, SEQ / 64), 256, 0, stream>>>(qkv, vt, a);
    gemm_small<false, false, false, 2, true><<<gPROJ, 256, 0, stream>>>(a, woT, nullptr, pproj, DIM, DIM);
    reduce_ln<<<SEQ, 256, 0, stream>>>(pproj, bo + (long)l * DIM,
                                       ln2w + (long)l * DIM, ln2b + (long)l * DIM, h, x);
    gemm4<true, true, true, true><<<gFFN1, 256, 0, stream>>>(x, w1T, b1 + (long)l * FFN, fbuf, FFN, DIM);
    gemm_small<false, false, false, 2, true><<<gFFN2, 256, 0, stream>>>(fbuf, w2T, nullptr, pffn2, DIM, FFN);
    const float* nw = (l < NLAYER - 1) ? ln1w + (long)(l + 1) * DIM : lnfw;
    const float* nb = (l < NLAYER - 1) ? ln1b + (long)(l + 1) * DIM : lnfb;
    reduce_ln<<<SEQ, 256, 0, stream>>>(pffn2, b2 + (long)l * DIM, nw, nb, h, x);
  }

  conv_bf16<<<2048, 256, 0, stream>>>(lmh, lmhB, (long)VOCAB * DIM / 4);
  gemm256<true><<<gV, 512, 0, stream>>>(x, lmhB, out, VOCAB, DIM);
}

// Round 9
// 1118.068 us; speedup vs baseline: 1.0297x; 1.0178x over previous
//
#include <hip/hip_runtime.h>
#include <math.h>
#include <stdint.h>

// GPT fwd, L=4 D=1024 H=16 HS=64 F=4096 V=50257 S=2048.
// Round 9: persistent gemm256p for lm_head (256 blocks, continuous K-step
// stream across 6-7 tiles/block, epilogue between counted waits -> pipeline
// never drains), merged per-layer prep_kernel, attn setprio.

#define SEQ 2048
#define DIM 1024
#define NHEAD 16
#define FFN 4096
#define VOCAB 50257
#define NLAYER 4
#define LNEPS 1e-5f
#define QKVD 3072
#define KVB 128

using bf16x8 = __attribute__((ext_vector_type(8))) short;
using s16x4  = __attribute__((ext_vector_type(4))) short;
using f32x4  = __attribute__((ext_vector_type(4))) float;
using fl4    = __attribute__((ext_vector_type(4))) float;

static __device__ __forceinline__ short f2bf(float f) {
  uint32_t u = __float_as_uint(f);
  u = (u + 0x7fffu + ((u >> 16) & 1u)) >> 16;
  return (short)u;
}
static __device__ __forceinline__ float bf2f(short s) {
  return __uint_as_float(((uint32_t)(uint16_t)s) << 16);
}
static __device__ __forceinline__ void gload_lds16(const void* g, void* l) {
  __builtin_amdgcn_global_load_lds((const __attribute__((address_space(1))) void*)g,
                                   (__attribute__((address_space(3))) void*)l, 16, 0, 0);
}

// ---------------- embedding (fp32 h) ----------------
__global__ void embed_kernel(const int* __restrict__ ids,
                             const float* __restrict__ tok,
                             const float* __restrict__ pos,
                             float* __restrict__ h) {
  int i = blockIdx.x * blockDim.x + threadIdx.x;
  if (i < SEQ * DIM) {
    int s = i / DIM, d = i % DIM;
    h[i] = tok[(long)ids[s] * DIM + d] + pos[i];
  }
}

// ---------------- layernorm: fp32 in -> bf16 out (layer0 ln1 only) ----------------
__global__ void ln_kernel(const float* __restrict__ x, const float* __restrict__ w,
                          const float* __restrict__ b, short* __restrict__ y) {
  int row = blockIdx.x;
  const float* xr = x + (long)row * DIM;
  short* yr = y + (long)row * DIM;
  int tid = threadIdx.x;
  float v0 = xr[tid], v1 = xr[tid + 256], v2 = xr[tid + 512], v3 = xr[tid + 768];
  __shared__ float red[8];
  float s = v0 + v1 + v2 + v3;
#pragma unroll
  for (int o = 32; o >= 1; o >>= 1) s += __shfl_xor(s, o);
  if ((tid & 63) == 0) red[tid >> 6] = s;
  __syncthreads();
  float mean = (red[0] + red[1] + red[2] + red[3]) * (1.f / DIM);
  float d0 = v0 - mean, d1 = v1 - mean, d2 = v2 - mean, d3 = v3 - mean;
  float q = d0 * d0 + d1 * d1 + d2 * d2 + d3 * d3;
#pragma unroll
  for (int o = 32; o >= 1; o >>= 1) q += __shfl_xor(q, o);
  if ((tid & 63) == 0) red[4 + (tid >> 6)] = q;
  __syncthreads();
  float var = (red[4] + red[5] + red[6] + red[7]) * (1.f / DIM);
  float rstd = rsqrtf(var + LNEPS);
  yr[tid]       = f2bf(d0 * rstd * w[tid] + b[tid]);
  yr[tid + 256] = f2bf(d1 * rstd * w[tid + 256] + b[tid + 256]);
  yr[tid + 512] = f2bf(d2 * rstd * w[tid + 512] + b[tid + 512]);
  yr[tid + 768] = f2bf(d3 * rstd * w[tid + 768] + b[tid + 768]);
}

// ---------------- fused: h += bias + part0 + part1; x = LN(h) bf16 ----------------
__global__ void reduce_ln(const float* __restrict__ part, const float* __restrict__ bias,
                          const float* __restrict__ lnw, const float* __restrict__ lnb,
                          float* __restrict__ h, short* __restrict__ x) {
  const long MN = (long)SEQ * DIM;
  int row = blockIdx.x, tid = threadIdx.x;
  long off = (long)row * DIM + tid * 4;
  fl4 hv = *(const fl4*)(h + off);
  fl4 p0 = *(const fl4*)(part + off);
  fl4 p1 = *(const fl4*)(part + MN + off);
  fl4 bv = *(const fl4*)(bias + tid * 4);
  float v[4];
#pragma unroll
  for (int u = 0; u < 4; u++) v[u] = hv[u] + p0[u] + p1[u] + bv[u];
  __shared__ float red[8];
  float s = v[0] + v[1] + v[2] + v[3];
#pragma unroll
  for (int o = 32; o >= 1; o >>= 1) s += __shfl_xor(s, o);
  if ((tid & 63) == 0) red[tid >> 6] = s;
  __syncthreads();
  float mean = (red[0] + red[1] + red[2] + red[3]) * (1.f / DIM);
  float d[4], q = 0.f;
#pragma unroll
  for (int u = 0; u < 4; u++) { d[u] = v[u] - mean; q += d[u] * d[u]; }
#pragma unroll
  for (int o = 32; o >= 1; o >>= 1) q += __shfl_xor(q, o);
  if ((tid & 63) == 0) red[4 + (tid >> 6)] = q;
  fl4 hw; hw[0] = v[0]; hw[1] = v[1]; hw[2] = v[2]; hw[3] = v[3];
  *(fl4*)(h + off) = hw;
  __syncthreads();
  float var = (red[4] + red[5] + red[6] + red[7]) * (1.f / DIM);
  float rstd = rsqrtf(var + LNEPS);
  fl4 w = *(const fl4*)(lnw + tid * 4);
  fl4 bb = *(const fl4*)(lnb + tid * 4);
  s16x4 o;
#pragma unroll
  for (int u = 0; u < 4; u++) o[u] = f2bf(d[u] * rstd * w[u] + bb[u]);
  *(s16x4*)(x + off) = o;
}

// ---------------- merged per-layer weight prep: 6 transposes + bias concat ----------------
// tiles: [0,1024) Wq/Wk/Wv/Wo (256 each), [1024,2048) W1, [2048,3072) W2,
// block 3072 = qkv bias concat. All transposes 64x64, fp32 [K][N] -> bf16 [N][K].
struct Prep {
  const float *wq, *wk, *wv, *wo, *w1, *w2, *bq, *bk, *bv;
  short *qkvT, *woT, *w1T, *w2T;
  float* bias3;
};
__global__ void prep_kernel(Prep p) {
  int t = blockIdx.x;
  if (t >= 3072) {
    for (int k = threadIdx.x; k < QKVD; k += 256)
      p.bias3[k] = k < DIM ? p.bq[k] : (k < 2 * DIM ? p.bk[k - DIM] : p.bv[k - 2 * DIM]);
    return;
  }
  const float* in; short* out; int Kd, Nd, r0, c0;
  if (t < 1024) {
    int m = t >> 8, lt = t & 255;
    const float* srcs[4] = {p.wq, p.wk, p.wv, p.wo};
    short* dsts[4] = {p.qkvT, p.qkvT + (long)DIM * DIM, p.qkvT + (long)2 * DIM * DIM, p.woT};
    in = srcs[m]; out = dsts[m]; Kd = DIM; Nd = DIM;
    c0 = (lt & 15) * 64; r0 = (lt >> 4) * 64;
  } else if (t < 2048) {
    int lt = t - 1024; in = p.w1; out = p.w1T; Kd = DIM; Nd = FFN;
    c0 = (lt & 63) * 64; r0 = (lt >> 6) * 64;
  } else {
    int lt = t - 2048; in = p.w2; out = p.w2T; Kd = FFN; Nd = DIM;
    c0 = (lt & 15) * 64; r0 = (lt >> 4) * 64;
  }
  __shared__ float ts[64][65];
  int tid = threadIdx.x;
  int lr = tid >> 4, lc4 = (tid & 15) * 4;
#pragma unroll
  for (int i = 0; i < 4; i++) {
    fl4 v = *(const fl4*)(in + (long)(r0 + lr + i * 16) * Nd + c0 + lc4);
    ts[lr + i * 16][lc4] = v[0]; ts[lr + i * 16][lc4 + 1] = v[1];
    ts[lr + i * 16][lc4 + 2] = v[2]; ts[lr + i * 16][lc4 + 3] = v[3];
  }
  __syncthreads();
#pragma unroll
  for (int i = 0; i < 2; i++) {
    int oc = (tid >> 3) + i * 32, seg = tid & 7;
    bf16x8 o;
#pragma unroll
    for (int u = 0; u < 8; u++) o[u] = f2bf(ts[seg * 8 + u][oc]);
    *(bf16x8*)(out + (long)(c0 + oc) * Kd + r0 + seg * 8) = o;
  }
}

// ---------------- V transpose: qkv[s][2D+c] -> vt[c][s] ----------------
__global__ void transpose_v(const short* __restrict__ qkv, short* __restrict__ vt) {
  __shared__ short t[64][72];
  int s0 = blockIdx.x * 64, c0 = blockIdx.y * 64;
  int tid = threadIdx.x;
#pragma unroll
  for (int i = 0; i < 2; i++) {
    int ca = i * 256 + tid;
    int row = ca >> 3, cp = ca & 7;
    bf16x8 v = *(const bf16x8*)(qkv + (long)(s0 + row) * QKVD + 2 * DIM + c0 + cp * 8);
    *(bf16x8*)&t[row][cp * 8] = v;
  }
  __syncthreads();
#pragma unroll
  for (int i = 0; i < 2; i++) {
    int ca = i * 256 + tid;
    int crow = ca >> 3, sp = ca & 7;
    bf16x8 o;
#pragma unroll
    for (int u = 0; u < 8; u++) o[u] = t[sp * 8 + u][crow];
    *(bf16x8*)(vt + (long)(c0 + crow) * SEQ + s0 + sp * 8) = o;
  }
}

// ---------------- fp32 -> bf16 convert (lm_head) ----------------
__global__ void conv_bf16(const float* __restrict__ in, short* __restrict__ out, long n4) {
  long i = (long)blockIdx.x * blockDim.x + threadIdx.x;
  long stride = (long)gridDim.x * blockDim.x;
  for (; i < n4; i += stride) {
    fl4 v = *(const fl4*)(in + i * 4);
    s16x4 o;
    o[0] = f2bf(v[0]); o[1] = f2bf(v[1]); o[2] = f2bf(v[2]); o[3] = f2bf(v[3]);
    *(s16x4*)(out + i * 4) = o;
  }
}

// ---------------- gemm_small: 64x128 tile, BK=32, 4 waves (QKV/proj/FFN2) ----------------
template <bool GELU, bool BIAS, bool OUTBF16, int KS, bool XCDSWZ>
__global__ __launch_bounds__(256, 4) void gemm_small(
    const short* __restrict__ A, const short* __restrict__ Bt,
    const float* __restrict__ bias, void* __restrict__ Cout, int N, int Kfull) {
  __shared__ short lds[3][(64 + 128) * 32];  // 3 x 12KB
  const int tid = threadIdx.x, wid = tid >> 6, lane = tid & 63;
  const int l16 = lane & 15, lg = lane >> 4;
  int bx = blockIdx.x, by = blockIdx.y;
  if (XCDSWZ) {
    int gx = gridDim.x, nwg = gx * gridDim.y;
    int flat = by * gx + bx;
    int nf = (flat & 7) * (nwg >> 3) + (flat >> 3);
    bx = nf % gx; by = nf / gx;
  }
  const long m0 = (long)bx * 64, n0 = (long)by * 128;
  const int K = Kfull / KS;
  const int kbase = blockIdx.z * K;
  const int NT = K / 32;
  const int wm = wid >> 1, wn = wid & 1;

#define STG(t, b)                                                               \
  {                                                                             \
    short* As_ = lds[b];                                                        \
    short* Bs_ = lds[b] + 64 * 32;                                              \
    int kk_ = kbase + (t) * 32;                                                 \
    {                                                                           \
      int row_ = tid >> 2, cp_ = tid & 3, c_ = cp_ ^ ((row_ >> 1) & 3);         \
      gload_lds16(A + (m0 + row_) * (long)Kfull + kk_ + c_ * 8,                 \
                  As_ + (wid * 64) * 8);                                        \
    }                                                                           \
    _Pragma("unroll")                                                           \
    for (int i_ = 0; i_ < 2; i_++) {                                            \
      int ca_ = i_ * 256 + tid;                                                 \
      int row_ = ca_ >> 2, cp_ = ca_ & 3, c_ = cp_ ^ ((row_ >> 1) & 3);         \
      gload_lds16(Bt + (long)(n0 + row_) * Kfull + kk_ + c_ * 8,                \
                  Bs_ + (i_ * 256 + wid * 64) * 8);                             \
    }                                                                           \
  }

  f32x4 acc[2][4] = {};
  STG(0, 0);
  STG(1, 1);
  asm volatile("s_waitcnt vmcnt(3)" ::: "memory");
  __builtin_amdgcn_s_barrier();
  __builtin_amdgcn_sched_barrier(0);

  for (int t = 0; t < NT; t++) {
    const int b = t % 3;
    if (t + 2 < NT) STG(t + 2, (t + 2) % 3);
    const short* As = lds[b];
    const short* Bs = lds[b] + 64 * 32;
    bf16x8 af[2], bfr[4];
#pragma unroll
    for (int m = 0; m < 2; m++) {
      int row = wm * 32 + m * 16 + l16;
      af[m] = *(const bf16x8*)((const char*)As + row * 64 + ((lg ^ ((row >> 1) & 3)) * 16));
    }
#pragma unroll
    for (int n = 0; n < 4; n++) {
      int row = wn * 64 + n * 16 + l16;
      bfr[n] = *(const bf16x8*)((const char*)Bs + row * 64 + ((lg ^ ((row >> 1) & 3)) * 16));
    }
    __builtin_amdgcn_s_setprio(1);
#pragma unroll
    for (int m = 0; m < 2; m++)
#pragma unroll
      for (int n = 0; n < 4; n++)
        acc[m][n] = __builtin_amdgcn_mfma_f32_16x16x32_bf16(af[m], bfr[n], acc[m][n], 0, 0, 0);
    __builtin_amdgcn_s_setprio(0);
    if (t + 2 < NT) {
      asm volatile("s_waitcnt vmcnt(3)" ::: "memory");
    } else if (t + 1 < NT) {
      asm volatile("s_waitcnt vmcnt(0)" ::: "memory");
    }
    if (t + 1 < NT) {
      __builtin_amdgcn_s_barrier();
      __builtin_amdgcn_sched_barrier(0);
    }
  }
#undef STG

  const int lr4 = lg * 4;
  if (KS == 1) {
#pragma unroll
    for (int m = 0; m < 2; m++)
#pragma unroll
      for (int n = 0; n < 4; n++)
#pragma unroll
        for (int r = 0; r < 4; r++) {
          long row = m0 + wm * 32 + m * 16 + lr4 + r;
          long col = n0 + wn * 64 + n * 16 + l16;
          float v = acc[m][n][r];
          if (BIAS) v += bias[col];
          if (GELU) v = 0.5f * v * (1.f + erff(v * 0.70710678118f));
          if (OUTBF16) ((short*)Cout)[row * (long)N + col] = f2bf(v);
          else ((float*)Cout)[row * (long)N + col] = v;
        }
  } else {
    long M = (long)gridDim.x * 64;
    float* P = (float*)Cout + (long)blockIdx.z * M * N;
#pragma unroll
    for (int m = 0; m < 2; m++)
#pragma unroll
      for (int n = 0; n < 4; n++)
#pragma unroll
        for (int r = 0; r < 4; r++) {
          long row = m0 + wm * 32 + m * 16 + lr4 + r;
          long col = n0 + wn * 64 + n * 16 + l16;
          P[row * (long)N + col] = acc[m][n][r];
        }
  }
}

// ---------------- gemm4: 128x128, BK=32, 3 blocks/CU (FFN1) ----------------
template <bool GELU, bool BIAS, bool OUTBF16, bool XCDSWZ>
__global__ __launch_bounds__(256, 3) void gemm4(
    const short* __restrict__ A, const short* __restrict__ Bt,
    const float* __restrict__ bias, void* __restrict__ Cout, int N, int Kfull) {
  __shared__ short lds[3][(128 + 128) * 32];  // 3 x 16KB
  const int tid = threadIdx.x, wid = tid >> 6, lane = tid & 63;
  const int l16 = lane & 15, lg = lane >> 4;
  int bx = blockIdx.x, by = blockIdx.y;
  if (XCDSWZ) {
    int gx = gridDim.x, nwg = gx * gridDim.y;
    int flat = by * gx + bx;
    int nf = (flat & 7) * (nwg >> 3) + (flat >> 3);
    bx = nf % gx; by = nf / gx;
  }
  const long m0 = (long)bx * 128, n0 = (long)by * 128;
  const int NT = Kfull / 32;
  const int wr = (wid >> 1) * 64, wc = (wid & 1) * 64;

#define STAGE4(t, b)                                                            \
  {                                                                             \
    short* As_ = lds[b];                                                        \
    short* Bs_ = lds[b] + 128 * 32;                                             \
    int kk_ = (t) * 32;                                                         \
    _Pragma("unroll")                                                           \
    for (int i_ = 0; i_ < 2; i_++) {                                            \
      int ca_ = i_ * 256 + tid;                                                 \
      int row_ = ca_ >> 2, cp_ = ca_ & 3, c_ = cp_ ^ ((row_ >> 1) & 3);         \
      gload_lds16(A + (m0 + row_) * (long)Kfull + kk_ + c_ * 8,                 \
                  As_ + (i_ * 256 + wid * 64) * 8);                             \
    }                                                                           \
    _Pragma("unroll")                                                           \
    for (int i_ = 0; i_ < 2; i_++) {                                            \
      int ca_ = i_ * 256 + tid;                                                 \
      int row_ = ca_ >> 2, cp_ = ca_ & 3, c_ = cp_ ^ ((row_ >> 1) & 3);         \
      gload_lds16(Bt + (long)(n0 + row_) * Kfull + kk_ + c_ * 8,                \
                  Bs_ + (i_ * 256 + wid * 64) * 8);                             \
    }                                                                           \
  }

  f32x4 acc[4][4] = {};
  STAGE4(0, 0);
  STAGE4(1, 1);
  asm volatile("s_waitcnt vmcnt(4)" ::: "memory");
  __builtin_amdgcn_s_barrier();
  __builtin_amdgcn_sched_barrier(0);

  for (int t = 0; t < NT; t++) {
    const int b = t % 3;
    if (t + 2 < NT) STAGE4(t + 2, (t + 2) % 3);
    const short* As = lds[b];
    const short* Bs = lds[b] + 128 * 32;
    bf16x8 af[4], bfr[4];
#pragma unroll
    for (int m = 0; m < 4; m++) {
      int row = wr + m * 16 + l16;
      af[m] = *(const bf16x8*)((const char*)As + row * 64 + ((lg ^ ((row >> 1) & 3)) * 16));
    }
#pragma unroll
    for (int n = 0; n < 4; n++) {
      int row = wc + n * 16 + l16;
      bfr[n] = *(const bf16x8*)((const char*)Bs + row * 64 + ((lg ^ ((row >> 1) & 3)) * 16));
    }
    __builtin_amdgcn_s_setprio(1);
#pragma unroll
    for (int m = 0; m < 4; m++)
#pragma unroll
      for (int n = 0; n < 4; n++)
        acc[m][n] = __builtin_amdgcn_mfma_f32_16x16x32_bf16(af[m], bfr[n], acc[m][n], 0, 0, 0);
    __builtin_amdgcn_s_setprio(0);
    if (t + 2 < NT) {
      asm volatile("s_waitcnt vmcnt(4)" ::: "memory");
    } else if (t + 1 < NT) {
      asm volatile("s_waitcnt vmcnt(0)" ::: "memory");
    }
    if (t + 1 < NT) {
      __builtin_amdgcn_s_barrier();
      __builtin_amdgcn_sched_barrier(0);
    }
  }
#undef STAGE4

  const int lr4 = lg * 4;
#pragma unroll
  for (int m = 0; m < 4; m++)
#pragma unroll
    for (int n = 0; n < 4; n++)
#pragma unroll
      for (int r = 0; r < 4; r++) {
        long row = m0 + wr + m * 16 + lr4 + r;
        long col = n0 + wc + n * 16 + l16;
        float v = acc[m][n][r];
        if (BIAS) v += bias[col];
        if (GELU) v = 0.5f * v * (1.f + erff(v * 0.70710678118f));
        if (OUTBF16) ((short*)Cout)[row * (long)N + col] = f2bf(v);
        else ((float*)Cout)[row * (long)N + col] = v;
      }
}

// ---------------- gemm256p: PERSISTENT 8-phase 256x256 GEMM (lm_head) ----------------
// 256 blocks, each walks tiles j = bid + t*256 (< totTiles) as ONE continuous
// K-step stream (step s -> tile s/16, k = (s%16)*64, buffer = s&1). The R7
// ledger is step-indexed and unchanged; epilogue stores happen right after
// the counted vmcnt(2)+barrier at each 16-step boundary, so the pipeline
// never drains until the block's last tile. Tile j -> (m = j&7, n = j>>3).
__global__ __launch_bounds__(512, 1) void gemm256p(
    const short* __restrict__ A, const short* __restrict__ Bt,
    float* __restrict__ C, int N, int K, int totTiles) {
  __shared__ short ldsA[2][256 * 64];
  __shared__ short ldsB[2][256 * 64];
  const int tid = threadIdx.x, wid = tid >> 6, lane = tid & 63;
  const int l16 = lane & 15, lg = lane >> 4;
  const int wm = wid >> 2, wn = wid & 3;
  const int bid = blockIdx.x, nb = gridDim.x;
  const int ntiles = (totTiles - bid + nb - 1) / nb;
  const int TOT = ntiles * 16;  // K-steps (K=1024 -> 16/tile)

  auto tileMN = [&](int ord, long& m0, long& n0) {
    int j = bid + ord * nb;
    m0 = (long)(j & 7) * 256;
    n0 = (long)(j >> 3) * 256;
  };
  auto SA = [&](int s, int r0) {
    long m0s, n0s; tileMN(s >> 4, m0s, n0s);
    int row = r0 + wid * 8 + (lane >> 3);
    int c = (lane & 7) ^ (row & 7);
    gload_lds16(A + (m0s + row) * (long)K + (s & 15) * 64 + c * 8,
                &ldsA[s & 1][(r0 + wid * 8) * 64]);
  };
  auto SB = [&](int s, int r0) {
    long m0s, n0s; tileMN(s >> 4, m0s, n0s);
    int row = r0 + wid * 8 + (lane >> 3);
    int c = (lane & 7) ^ (row & 7);
    int rowb = (int)n0s + row;
    if (rowb > N - 1) rowb = N - 1;
    gload_lds16(Bt + (long)rowb * K + (s & 15) * 64 + c * 8,
                &ldsB[s & 1][(r0 + wid * 8) * 64]);
  };

  f32x4 acc[8][4] = {};
  bf16x8 bfr[4][2];

  auto PH = [&](int b, int q) {
    bf16x8 af[2][2];
    if (q == 0) {
#pragma unroll
      for (int nf = 0; nf < 4; nf++) {
        int row = wn * 64 + nf * 16 + l16;
#pragma unroll
        for (int ks = 0; ks < 2; ks++)
          bfr[nf][ks] = *(const bf16x8*)((const char*)&ldsB[b][0] + row * 128 +
                                         (((ks * 4 + lg) ^ (row & 7)) * 16));
      }
    }
#pragma unroll
    for (int j = 0; j < 2; j++) {
      int row = wm * 128 + (q * 2 + j) * 16 + l16;
#pragma unroll
      for (int ks = 0; ks < 2; ks++)
        af[j][ks] = *(const bf16x8*)((const char*)&ldsA[b][0] + row * 128 +
                                     (((ks * 4 + lg) ^ (row & 7)) * 16));
    }
    __builtin_amdgcn_s_barrier();
    __builtin_amdgcn_s_setprio(1);
#pragma unroll
    for (int ks = 0; ks < 2; ks++)
#pragma unroll
      for (int j = 0; j < 2; j++)
#pragma unroll
        for (int nf = 0; nf < 4; nf++)
          acc[q * 2 + j][nf] =
              __builtin_amdgcn_mfma_f32_16x16x32_bf16(af[j][ks], bfr[nf][ks],
                                                      acc[q * 2 + j][nf], 0, 0, 0);
    __builtin_amdgcn_s_setprio(0);
  };

  // prologue: step 0 fully + A0,A2 of step 1; vmcnt(2) leaves step1's pair
  SA(0, 0); SA(0, 64); SA(0, 128); SA(0, 192);
  SB(0, 0); SB(0, 64); SB(0, 128); SB(0, 192);
  SA(1, 0); SA(1, 128);
  asm volatile("s_waitcnt vmcnt(2)" ::: "memory");
  __builtin_amdgcn_s_barrier();

  for (int it = 0; it < TOT / 2; it++) {
    const int e = 2 * it, o = e + 1;
    const bool more = (e + 2) < TOT;
    SA(o, 64); SA(o, 192);
    PH(0, 0);
    __builtin_amdgcn_s_barrier();
    SB(o, 0); SB(o, 64);
    PH(0, 1);
    __builtin_amdgcn_s_barrier();
    SB(o, 128); SB(o, 192);
    PH(0, 2);
    __builtin_amdgcn_s_barrier();
    if (more) { SA(e + 2, 0); SA(e + 2, 128); }
    PH(0, 3);
    if (more) asm volatile("s_waitcnt vmcnt(2)" ::: "memory");
    else      asm volatile("s_waitcnt vmcnt(0)" ::: "memory");
    __builtin_amdgcn_s_barrier();
    if (more) { SA(e + 2, 64); SA(e + 2, 192); }
    PH(1, 0);
    __builtin_amdgcn_s_barrier();
    if (more) { SB(e + 2, 0); SB(e + 2, 64); }
    PH(1, 1);
    __builtin_amdgcn_s_barrier();
    if (more) { SB(e + 2, 128); SB(e + 2, 192); }
    PH(1, 2);
    __builtin_amdgcn_s_barrier();
    if (more) { SA(e + 3, 0); SA(e + 3, 128); }
    PH(1, 3);
    if (more) {
      asm volatile("s_waitcnt vmcnt(2)" ::: "memory");
      __builtin_amdgcn_s_barrier();
    } else {
      asm volatile("s_waitcnt vmcnt(0)" ::: "memory");
    }
    if ((o & 15) == 15) {  // output-tile boundary: store + zero acc
      long m0c, n0c; tileMN(o >> 4, m0c, n0c);
#pragma unroll
      for (int mf = 0; mf < 8; mf++)
#pragma unroll
        for (int nf = 0; nf < 4; nf++)
#pragma unroll
          for (int r = 0; r < 4; r++) {
            long row = m0c + wm * 128 + mf * 16 + lg * 4 + r;
            long col = n0c + wn * 64 + nf * 16 + l16;
            if (col < N) C[row * (long)N + col] = acc[mf][nf][r];
            acc[mf][nf][r] = 0.f;
          }
    }
  }
}

// ---------------- MFMA flash attention, KVBLK=128, dbuf staging + setprio ----------------
__global__ __launch_bounds__(256) void attn_mfma(const short* __restrict__ qkv,
                                                 const short* __restrict__ vtg,
                                                 short* __restrict__ Oa) {
  int hh = blockIdx.x, qb = blockIdx.y;
  int q0 = qb * 64;
  int tid = threadIdx.x, wv = tid >> 6, lane = tid & 63;
  int l16 = lane & 15, lg = lane >> 4;
  int hcol = hh * 64;
  __shared__ short Ks[2][KVB * 64];
  __shared__ short Vt[2][64 * KVB];
  __shared__ short Pl[4][16 * KVB];

  bf16x8 qf[2];
  {
    const short* qrow = qkv + (long)(q0 + wv * 16 + l16) * QKVD + hcol;
#pragma unroll
    for (int dc = 0; dc < 2; dc++) {
      bf16x8 t = *(const bf16x8*)(qrow + dc * 32 + lg * 8);
#pragma unroll
      for (int j = 0; j < 8; j++) t[j] = f2bf(bf2f(t[j]) * 0.125f);
      qf[dc] = t;
    }
  }
  f32x4 of[4] = {};
  float mrun[4], lrun[4];
#pragma unroll
  for (int r = 0; r < 4; r++) { mrun[r] = -3e38f; lrun[r] = 0.f; }

#define STAGEKV(kt_, b_)                                                        \
  {                                                                             \
    int k0_ = (kt_) * KVB;                                                      \
    _Pragma("unroll")                                                           \
    for (int i = 0; i < 4; i++) {                                               \
      int ca = i * 256 + tid;                                                   \
      int row = ca >> 3, cp = ca & 7, c = cp ^ (row & 7);                       \
      gload_lds16(qkv + (long)(k0_ + row) * QKVD + DIM + hcol + c * 8,          \
                  (short*)Ks[b_] + (i * 256 + wv * 64) * 8);                    \
    }                                                                           \
    _Pragma("unroll")                                                           \
    for (int i = 0; i < 4; i++) {                                               \
      int ca = i * 256 + tid;                                                   \
      int row = ca >> 4, cp = ca & 15, c = cp ^ (row & 7);                      \
      gload_lds16(vtg + (long)(hcol + row) * SEQ + k0_ + c * 8,                 \
                  (short*)Vt[b_] + (i * 256 + wv * 64) * 8);                    \
    }                                                                           \
  }

  int nt = qb / 2 + 1;
  STAGEKV(0, 0);
  asm volatile("s_waitcnt vmcnt(0)" ::: "memory");
  __builtin_amdgcn_s_barrier();

  for (int kt = 0; kt < nt; kt++) {
    const int cur = kt & 1;
    if (kt + 1 < nt) STAGEKV(kt + 1, cur ^ 1);
    int k0 = kt * KVB;

    f32x4 sacc[8] = {};
    __builtin_amdgcn_s_setprio(1);
#pragma unroll
    for (int kc = 0; kc < 8; kc++) {
      int row = kc * 16 + l16;
#pragma unroll
      for (int dc = 0; dc < 2; dc++) {
        bf16x8 kf = *(const bf16x8*)((const char*)Ks[cur] + row * 128 + (((dc * 4 + lg) ^ (row & 7)) * 16));
        sacc[kc] = __builtin_amdgcn_mfma_f32_16x16x32_bf16(qf[dc], kf, sacc[kc], 0, 0, 0);
      }
    }
    __builtin_amdgcn_s_setprio(0);

    float sv[8][4], pf[8][4];
#pragma unroll
    for (int kc = 0; kc < 8; kc++)
#pragma unroll
      for (int r = 0; r < 4; r++) sv[kc][r] = sacc[kc][r];
    if (kt == nt - 1) {
#pragma unroll
      for (int kc = 0; kc < 8; kc++)
#pragma unroll
        for (int r = 0; r < 4; r++) {
          int kg = k0 + kc * 16 + l16;
          int rg = q0 + wv * 16 + lg * 4 + r;
          if (kg > rg) sv[kc][r] = -3e38f;
        }
    }
    float corr[4];
#pragma unroll
    for (int r = 0; r < 4; r++) {
      float m01 = fmaxf(sv[0][r], sv[1][r]), m23 = fmaxf(sv[2][r], sv[3][r]);
      float m45 = fmaxf(sv[4][r], sv[5][r]), m67 = fmaxf(sv[6][r], sv[7][r]);
      float mt = fmaxf(fmaxf(m01, m23), fmaxf(m45, m67));
#pragma unroll
      for (int o = 8; o >= 1; o >>= 1) mt = fmaxf(mt, __shfl_xor(mt, o));
      float mn = fmaxf(mrun[r], mt);
      corr[r] = __expf(mrun[r] - mn);
      mrun[r] = mn;
      float ps = 0.f;
#pragma unroll
      for (int kc = 0; kc < 8; kc++) {
        float p = __expf(sv[kc][r] - mn);
        pf[kc][r] = p;
        ps += p;
      }
#pragma unroll
      for (int o = 8; o >= 1; o >>= 1) ps += __shfl_xor(ps, o);
      lrun[r] = lrun[r] * corr[r] + ps;
    }
#pragma unroll
    for (int c = 0; c < 4; c++)
#pragma unroll
      for (int r = 0; r < 4; r++) of[c][r] *= corr[r];
#pragma unroll
    for (int kc = 0; kc < 8; kc++)
#pragma unroll
      for (int r = 0; r < 4; r++) {
        int row = lg * 4 + r, col = kc * 16 + l16;
        int chunk = col >> 3;
        *(short*)((char*)Pl[wv] + row * 256 + ((chunk ^ (row & 7)) * 16) + (col & 7) * 2) = f2bf(pf[kc][r]);
      }
    bf16x8 pfr[4];
#pragma unroll
    for (int kc2 = 0; kc2 < 4; kc2++) {
      int cl = kc2 * 4 + lg;
      pfr[kc2] = *(const bf16x8*)((const char*)Pl[wv] + l16 * 256 + ((cl ^ (l16 & 7)) * 16));
    }
    __builtin_amdgcn_s_setprio(1);
#pragma unroll
    for (int c = 0; c < 4; c++)
#pragma unroll
      for (int kc2 = 0; kc2 < 4; kc2++) {
        int vrow = c * 16 + l16;
        int cl = kc2 * 4 + lg;
        bf16x8 vf = *(const bf16x8*)((const char*)Vt[cur] + vrow * 256 + ((cl ^ (vrow & 7)) * 16));
        of[c] = __builtin_amdgcn_mfma_f32_16x16x32_bf16(pfr[kc2], vf, of[c], 0, 0, 0);
      }
    __builtin_amdgcn_s_setprio(0);
    if (kt + 1 < nt) {
      asm volatile("s_waitcnt vmcnt(0)" ::: "memory");
      __builtin_amdgcn_s_barrier();
      __builtin_amdgcn_sched_barrier(0);
    }
  }
#undef STAGEKV
#pragma unroll
  for (int c = 0; c < 4; c++)
#pragma unroll
    for (int r = 0; r < 4; r++) {
      int rowg = q0 + wv * 16 + lg * 4 + r;
      int colg = hcol + c * 16 + l16;
      Oa[(long)rowg * DIM + colg] = f2bf(of[c][r] / lrun[r]);
    }
}

// ---------------- orchestration ----------------
extern "C" void kernel_launch(void* const* d_in, const int* in_sizes, int n_in,
                              void* d_out, int out_size, void* d_ws, size_t ws_size,
                              hipStream_t stream) {
  const int* ids = (const int*)d_in[0];
  const float* tok = (const float*)d_in[1];
  const float* pos = (const float*)d_in[2];
  const float* Wq = (const float*)d_in[3];
  const float* bq = (const float*)d_in[4];
  const float* Wk = (const float*)d_in[5];
  const float* bk = (const float*)d_in[6];
  const float* Wv = (const float*)d_in[7];
  const float* bv = (const float*)d_in[8];
  const float* Wo = (const float*)d_in[9];
  const float* bo = (const float*)d_in[10];
  const float* W1 = (const float*)d_in[11];
  const float* b1 = (const float*)d_in[12];
  const float* W2 = (const float*)d_in[13];
  const float* b2 = (const float*)d_in[14];
  const float* ln1w = (const float*)d_in[15];
  const float* ln1b = (const float*)d_in[16];
  const float* ln2w = (const float*)d_in[17];
  const float* ln2b = (const float*)d_in[18];
  const float* lnfw = (const float*)d_in[19];
  const float* lnfb = (const float*)d_in[20];
  const float* lmh = (const float*)d_in[21];
  float* out = (float*)d_out;

  char* wsb = (char*)d_ws;
  float* h = (float*)wsb;                           // 8 MB fp32 residual
  short* x = (short*)(wsb + 8388608);               // 4 MB bf16 LN out
  char* big = wsb + 8388608 + 4194304;
  short* qkv  = (short*)big;                        // 12 MB   [S][3072]
  short* a    = (short*)(big + 12582912);           // 4 MB    [S][1024]
  short* vt   = (short*)(big + 16777216);           // 4 MB    [1024][S]
  short* fbuf = (short*)(big + 20971520);           // 16 MB   [S][4096]
  float* pproj = (float*)fbuf;                      // proj partials: 2x8MB
  float* pffn2 = (float*)big;                       // ffn2 partials: 2x8MB (qkv+a free)
  char* wdyn = big + 37748736;
  short* wqkvT = (short*)wdyn;                      // 6 MB  [3072][1024]
  short* woT   = (short*)(wdyn + 6291456);          // 2 MB  [1024][1024]
  short* w1T   = (short*)(wdyn + 8388608);          // 8 MB  [4096][1024]
  short* w2T   = (short*)(wdyn + 16777216);         // 8 MB  [1024][4096]
  float* bias3 = (float*)(wdyn + 25165824);         // 12 KB
  short* lmhB = (short*)big;                        // 103 MB, reused after layers

  embed_kernel<<<(SEQ * DIM + 255) / 256, 256, 0, stream>>>(ids, tok, pos, h);
  ln_kernel<<<SEQ, 256, 0, stream>>>(h, ln1w, ln1b, x);  // layer 0 ln1

  dim3 gQKV(SEQ / 64, QKVD / 128);                  // 32 x 24 = 768
  dim3 gPROJ(SEQ / 64, DIM / 128, 2);               // 32 x 8 x 2 = 512
  dim3 gFFN1(SEQ / 128, FFN / 128);                 // 16 x 32 = 512
  dim3 gFFN2(SEQ / 64, DIM / 128, 2);               // 32 x 8 x 2 = 512

  for (int l = 0; l < NLAYER; l++) {
    Prep p;
    p.wq = Wq + (long)l * DIM * DIM; p.wk = Wk + (long)l * DIM * DIM;
    p.wv = Wv + (long)l * DIM * DIM; p.wo = Wo + (long)l * DIM * DIM;
    p.w1 = W1 + (long)l * DIM * FFN; p.w2 = W2 + (long)l * FFN * DIM;
    p.bq = bq + (long)l * DIM; p.bk = bk + (long)l * DIM; p.bv = bv + (long)l * DIM;
    p.qkvT = wqkvT; p.woT = woT; p.w1T = w1T; p.w2T = w2T; p.bias3 = bias3;
    prep_kernel<<<3073, 256, 0, stream>>>(p);

    gemm_small<false, true, true, 1, true><<<gQKV, 256, 0, stream>>>(x, wqkvT, bias3, qkv, QKVD, DIM);
    transpose_v<<<dim3(SEQ / 64, DIM / 64), 256, 0, stream>>>(qkv, vt);
    attn_mfma<<<dim3(NHEAD, SEQ / 64), 256, 0, stream>>>(qkv, vt, a);
    gemm_small<false, false, false, 2, true><<<gPROJ, 256, 0, stream>>>(a, woT, nullptr, pproj, DIM, DIM);
    reduce_ln<<<SEQ, 256, 0, stream>>>(pproj, bo + (long)l * DIM,
                                       ln2w + (long)l * DIM, ln2b + (long)l * DIM, h, x);
    gemm4<true, true, true, true><<<gFFN1, 256, 0, stream>>>(x, w1T, b1 + (long)l * FFN, fbuf, FFN, DIM);
    gemm_small<false, false, false, 2, true><<<gFFN2, 256, 0, stream>>>(fbuf, w2T, nullptr, pffn2, DIM, FFN);
    const float* nw = (l < NLAYER - 1) ? ln1w + (long)(l + 1) * DIM : lnfw;
    const float* nb = (l < NLAYER - 1) ? ln1b + (long)(l + 1) * DIM : lnfb;
    reduce_ln<<<SEQ, 256, 0, stream>>>(pffn2, b2 + (long)l * DIM, nw, nb, h, x);
  }

  conv_bf16<<<2048, 256, 0, stream>>>(lmh, lmhB, (long)VOCAB * DIM / 4);
  gemm256p<<<dim3(256), 512, 0, stream>>>(x, lmhB, out, VOCAB, DIM,
                                          (SEQ / 256) * ((VOCAB + 255) / 256));
}